// Round 1
// baseline (2305.841 us; speedup 1.0000x reference)
//
#include <hip/hip_runtime.h>
#include <math.h>

#define NN 2048
#define DIMF 256
#define HIDN 128
#define NG 8
#define NEDGES 32768
#define W32 32
#define TRI_CAP 131072

typedef unsigned long long u64;
typedef unsigned char u8;

// ---------------- build adjacency ----------------
__global__ void k_init(u64* __restrict__ rowbits, int* __restrict__ segstart) {
  int i = blockIdx.x * blockDim.x + threadIdx.x;
  for (int k = i; k < NN * W32; k += gridDim.x * blockDim.x) rowbits[k] = 0ull;
  if (i <= NG) segstart[i] = NN;
}

__global__ void k_edges(const int* __restrict__ ei, u64* __restrict__ rowbits) {
  int e = blockIdx.x * blockDim.x + threadIdx.x;
  if (e >= NEDGES) return;
  int u = ei[e], v = ei[NEDGES + e];
  atomicOr(&rowbits[((size_t)u << 5) + (v >> 6)], 1ull << (v & 63));
}

__global__ void k_deg(const u64* __restrict__ rowbits, int* __restrict__ deg) {
  int i = blockIdx.x * blockDim.x + threadIdx.x;
  if (i >= NN) return;
  int c = 0;
  for (int w = 0; w < W32; ++w) c += __popcll(rowbits[(i << 5) + w]);
  deg[i] = c;
}

// exclusive scan of 2048 ints -> out[0..2048]
__global__ void k_scan2048(const int* __restrict__ in, int* __restrict__ out) {
  __shared__ int part[256];
  int t = threadIdx.x;
  int v[8]; int s = 0;
  for (int k = 0; k < 8; ++k) { v[k] = in[t * 8 + k]; s += v[k]; }
  part[t] = s;
  __syncthreads();
  for (int off = 1; off < 256; off <<= 1) {
    int y = (t >= off) ? part[t - off] : 0;
    __syncthreads();
    part[t] += y;
    __syncthreads();
  }
  int run = part[t] - s;
  for (int k = 0; k < 8; ++k) { out[t * 8 + k] = run; run += v[k]; }
  if (t == 255) out[NN] = part[255];
}

__global__ void k_extract(const u64* __restrict__ rowbits, const int* __restrict__ rp, int* __restrict__ col) {
  int i = blockIdx.x * blockDim.x + threadIdx.x;
  if (i >= NN) return;
  int o = rp[i];
  for (int w = 0; w < W32; ++w) {
    u64 b = rowbits[(i << 5) + w];
    while (b) { col[o++] = (w << 6) + __builtin_ctzll(b); b &= b - 1; }
  }
}

// ordered triangle pairs (a,b): a,b in N(i), A_ab=1
__global__ void k_tricnt(const u64* __restrict__ rowbits, const int* __restrict__ rp,
                         const int* __restrict__ col, int* __restrict__ cnt) {
  int i = blockIdx.x * blockDim.x + threadIdx.x;
  if (i >= NN) return;
  const u64* ri = rowbits + ((size_t)i << 5);
  int c = 0;
  for (int e = rp[i]; e < rp[i + 1]; ++e) {
    const u64* ra = rowbits + ((size_t)col[e] << 5);
    for (int w = 0; w < W32; ++w) c += __popcll(ra[w] & ri[w]);
  }
  cnt[i] = c;
}

__global__ void k_trifill(const u64* __restrict__ rowbits, const int* __restrict__ rp,
                          const int* __restrict__ col, const int* __restrict__ tp,
                          int2* __restrict__ tri) {
  int i = blockIdx.x * blockDim.x + threadIdx.x;
  if (i >= NN) return;
  const u64* ri = rowbits + ((size_t)i << 5);
  int o = tp[i];
  for (int e = rp[i]; e < rp[i + 1]; ++e) {
    int a = col[e];
    const u64* ra = rowbits + ((size_t)a << 5);
    for (int w = 0; w < W32; ++w) {
      u64 b = ra[w] & ri[w];
      while (b) {
        int j = (w << 6) + __builtin_ctzll(b);
        if (o < TRI_CAP) tri[o] = make_int2(a, j);
        ++o;
        b &= b - 1;
      }
    }
  }
}

// ---------------- entropy term ----------------
__global__ void k_V(const float* __restrict__ x, const int* __restrict__ rp,
                    const int* __restrict__ col, float* __restrict__ V) {
  int i = blockIdx.x; int t = threadIdx.x; // 256 threads = dims
  float xi = x[i * DIMF + t];
  float s1 = 0.f, s2 = 0.f;
  int r0 = rp[i], r1 = rp[i + 1];
  for (int e = r0; e < r1; ++e) {
    float xj = x[col[e] * DIMF + t];
    s1 += xj; s2 += xj * xj;
  }
  float dg = (float)(r1 - r0);
  float val = dg * xi * xi - 2.f * xi * s1 + s2;
  __shared__ double red[DIMF];
  red[t] = (double)val * (double)val;
  __syncthreads();
  for (int off = DIMF / 2; off > 0; off >>= 1) { if (t < off) red[t] += red[t + off]; __syncthreads(); }
  if (t == 0) V[i] = (float)sqrt(red[0]);
}

__global__ void k_bounds(const int* __restrict__ batch, int* __restrict__ segstart) {
  int i = blockIdx.x * blockDim.x + threadIdx.x;
  if (i >= NN) return;
  if (i == 0 || batch[i] != batch[i - 1]) segstart[batch[i]] = i;
}

__global__ void k_soft(const float* __restrict__ V, const int* __restrict__ segstart,
                       float* __restrict__ ent, double* __restrict__ seggamma) {
  int g = blockIdx.x; int t = threadIdx.x;
  int s = segstart[g];
  int e = NN;
  for (int gg = g + 1; gg <= NG; ++gg) { int v = segstart[gg]; if (v < e) e = v; }
  if (s >= e) { if (t == 0) seggamma[g] = 0.0; return; }
  __shared__ float fm[256];
  __shared__ double dd[256];
  float m = -3.0e38f;
  for (int i = s + t; i < e; i += 256) m = fmaxf(m, V[i]);
  fm[t] = m; __syncthreads();
  for (int off = 128; off > 0; off >>= 1) { if (t < off) fm[t] = fmaxf(fm[t], fm[t + off]); __syncthreads(); }
  float mx = fm[0];
  __syncthreads();
  double sum = 0.0;
  for (int i = s + t; i < e; i += 256) sum += exp((double)V[i] - (double)mx);
  dd[t] = sum; __syncthreads();
  for (int off = 128; off > 0; off >>= 1) { if (t < off) dd[t] += dd[t + off]; __syncthreads(); }
  double tot = dd[0];
  __syncthreads();
  double gs = 0.0;
  for (int i = s + t; i < e; i += 256) {
    double P = exp((double)V[i] - (double)mx) / tot;
    float ev = (P > 0.0) ? (float)(-P * log(P)) : 0.f;
    ent[i] = ev;
    gs += (double)ev;
  }
  dd[t] = gs; __syncthreads();
  for (int off = 128; off > 0; off >>= 1) { if (t < off) dd[t] += dd[t + off]; __syncthreads(); }
  if (t == 0) seggamma[g] = dd[0];
}

// ---------------- GIN MLPs ----------------
__global__ void k_agg1(const float* __restrict__ ent, const int* __restrict__ rp,
                       const int* __restrict__ col, float* __restrict__ agg) {
  int i = blockIdx.x * blockDim.x + threadIdx.x;
  if (i >= NN) return;
  float a = ent[i];
  for (int e = rp[i]; e < rp[i + 1]; ++e) a += ent[col[e]];
  agg[i] = a;
}

__global__ void k_lin1(const float* __restrict__ agg, const float* __restrict__ w,
                       const float* __restrict__ b, float* __restrict__ t) {
  int idx = blockIdx.x * blockDim.x + threadIdx.x;
  if (idx >= NN * HIDN) return;
  int i = idx >> 7, k = idx & 127;
  float v = agg[i] * w[k] + b[k];
  t[idx] = v > 0.f ? v : 0.f;
}

__global__ void k_bn(const float* __restrict__ t, const float* __restrict__ g,
                     const float* __restrict__ be, float* __restrict__ scale,
                     float* __restrict__ shift) {
  int k = blockIdx.x; int tid = threadIdx.x; // 256 threads per column
  __shared__ double red[256];
  double s = 0.0;
  for (int i = tid; i < NN; i += 256) s += (double)t[i * HIDN + k];
  red[tid] = s; __syncthreads();
  for (int off = 128; off > 0; off >>= 1) { if (tid < off) red[tid] += red[tid + off]; __syncthreads(); }
  double mu = red[0] / NN;
  __syncthreads();
  double v = 0.0;
  for (int i = tid; i < NN; i += 256) { double dv = (double)t[i * HIDN + k] - mu; v += dv * dv; }
  red[tid] = v; __syncthreads();
  for (int off = 128; off > 0; off >>= 1) { if (tid < off) red[tid] += red[tid + off]; __syncthreads(); }
  if (tid == 0) {
    float var = (float)(red[0] / NN);
    float sc = g[k] / sqrtf(var + 1e-5f);
    scale[k] = sc;
    shift[k] = be[k] - (float)mu * sc;
  }
}

template<int PRE, int RELU>
__global__ void k_mm(const float* __restrict__ in, const float* __restrict__ Wm,
                     const float* __restrict__ bias, const float* __restrict__ scale,
                     const float* __restrict__ shift, float* __restrict__ out) {
  __shared__ float ti[8][HIDN];
  int r0 = blockIdx.x * 8; int t = threadIdx.x; // 128 threads
  for (int r = 0; r < 8; ++r) {
    float v = in[(r0 + r) * HIDN + t];
    if (PRE) v = v * scale[t] + shift[t];
    ti[r][t] = v;
  }
  __syncthreads();
  float acc[8];
  #pragma unroll
  for (int r = 0; r < 8; ++r) acc[r] = 0.f;
  for (int k = 0; k < HIDN; ++k) {
    float w = Wm[k * HIDN + t];
    #pragma unroll
    for (int r = 0; r < 8; ++r) acc[r] += ti[r][k] * w;
  }
  for (int r = 0; r < 8; ++r) {
    float v = acc[r] + bias[t];
    if (RELU) v = fmaxf(v, 0.f);
    out[(r0 + r) * HIDN + t] = v;
  }
}

__global__ void k_agg128(const float* __restrict__ h, const int* __restrict__ rp,
                         const int* __restrict__ col, float* __restrict__ agg) {
  int i = blockIdx.x; int t = threadIdx.x; // 128 threads
  float a = h[i * HIDN + t];
  for (int e = rp[i]; e < rp[i + 1]; ++e) a += h[col[e] * HIDN + t];
  agg[i * HIDN + t] = a;
}

__global__ void k_lin3(const float* __restrict__ tn, const float* __restrict__ scale,
                       const float* __restrict__ shift, const float* __restrict__ w32,
                       const float* __restrict__ b32, float* __restrict__ p) {
  int i = blockIdx.x; int t = threadIdx.x; // 128
  float v = (tn[i * HIDN + t] * scale[t] + shift[t]) * w32[t];
  __shared__ float red[HIDN];
  red[t] = v; __syncthreads();
  for (int off = 64; off > 0; off >>= 1) { if (t < off) red[t] += red[t + off]; __syncthreads(); }
  if (t == 0) {
    float h3 = red[0] + b32[0];
    p[i] = 1.f / (1.f + expf(-h3));
  }
}

// ---------------- loss ----------------
__global__ void k_q0(const float* __restrict__ p, const int* __restrict__ rp,
                     const int* __restrict__ col, float* __restrict__ q0) {
  int i = blockIdx.x * blockDim.x + threadIdx.x;
  if (i >= NN) return;
  float s = 0.f;
  for (int e = rp[i]; e < rp[i + 1]; ++e) s += p[col[e]];
  q0[i] = s;
}

__global__ void k_loss(const float* __restrict__ ent, const float* __restrict__ p,
                       const float* __restrict__ q0, const double* __restrict__ seggamma,
                       double* __restrict__ scal) {
  __shared__ double ra[256], rb[256];
  int t = threadIdx.x;
  double a = 0.0, b = 0.0;
  for (int i = t; i < NN; i += 256) { a += (double)ent[i] * (double)p[i]; b += (double)p[i] * (double)q0[i]; }
  ra[t] = a; rb[t] = b; __syncthreads();
  for (int off = 128; off > 0; off >>= 1) {
    if (t < off) { ra[t] += ra[t + off]; rb[t] += rb[t + off]; }
    __syncthreads();
  }
  if (t == 0) {
    double gamma = 0.0;
    for (int g = 0; g < NG; ++g) gamma += seggamma[g];
    scal[0] = gamma; scal[1] = ra[0]; scal[2] = rb[0];
    scal[3] = gamma - ra[0] + rb[0];
  }
}

// ---------------- sort (descending p, stable) ----------------
__global__ void k_keys(const float* __restrict__ p, u64* __restrict__ keys) {
  int i = blockIdx.x * blockDim.x + threadIdx.x;
  if (i >= NN) return;
  unsigned int b = __float_as_uint(p[i]);
  unsigned int s = (b & 0x80000000u) ? ~b : (b | 0x80000000u);
  keys[i] = ((u64)(~s) << 32) | (unsigned int)i;
}

__global__ void k_sort(const u64* __restrict__ keys, int* __restrict__ order) {
  __shared__ u64 s[NN];
  int t = threadIdx.x; // 1024
  s[t] = keys[t]; s[t + 1024] = keys[t + 1024];
  __syncthreads();
  for (int k = 2; k <= NN; k <<= 1) {
    for (int j = k >> 1; j > 0; j >>= 1) {
      for (int i = t; i < NN; i += 1024) {
        int ixj = i ^ j;
        if (ixj > i) {
          bool up = ((i & k) == 0);
          u64 a = s[i], b = s[ixj];
          if ((a > b) == up) { s[i] = b; s[ixj] = a; }
        }
      }
      __syncthreads();
    }
  }
  order[t] = (int)(s[t] & 0xFFFFFFFFull);
  order[t + 1024] = (int)(s[t + 1024] & 0xFFFFFFFFull);
}

// ---------------- greedy sequential selection (1 wave) ----------------
__global__ void __launch_bounds__(64) k_greedy(
    const int* __restrict__ rp, const int* __restrict__ col,
    const int* __restrict__ tp, const int2* __restrict__ tri,
    const int* __restrict__ order, const float* __restrict__ p,
    const float* __restrict__ ent, const float* __restrict__ q0,
    const double* __restrict__ scal, u8* __restrict__ selb_g) {
  __shared__ float d[NN], q[NN], del[NN], entl[NN];
  __shared__ int ordl[NN];
  __shared__ u8 selb[NN], rejb[NN];
  int t = threadIdx.x;
  for (int i = t; i < NN; i += 64) {
    d[i] = p[i]; q[i] = q0[i]; del[i] = 0.f; entl[i] = ent[i];
    ordl[i] = order[i]; selb[i] = 0; rejb[i] = 0;
  }
  double gamma = scal[0], ed = scal[1], dAd = scal[2], loss = scal[3];
  __syncthreads();
  for (int step = 0; step < NN; ++step) {
    int idx = ordl[step];
    int r0 = rp[idx], r1 = rp[idx + 1];
    if (r1 == r0) { if (t == 0) selb[idx] = 1; __syncthreads(); continue; }
    if (selb[idx] || rejb[idx]) { __syncthreads(); continue; }
    double s1 = 0.0, s2 = 0.0, sn = 0.0, st = 0.0;
    for (int e = r0 + t; e < r1; e += 64) {
      int j = col[e];
      float dj = d[j];
      del[j] = -dj;
      s1 -= (double)entl[j] * (double)dj;
      s2 -= (double)q[j] * (double)dj;
      sn -= (double)dj;
    }
    float d0 = 1.f - d[idx];
    if (t == 0) {
      del[idx] = d0;
      s1 += (double)entl[idx] * (double)d0;
      s2 += (double)q[idx] * (double)d0;
    }
    __syncthreads();
    int t0 = tp[idx]; int t1 = tp[idx + 1];
    if (t0 > TRI_CAP) t0 = TRI_CAP;
    if (t1 > TRI_CAP) t1 = TRI_CAP;
    for (int e = t0 + t; e < t1; e += 64) {
      int2 ab = tri[e];
      st += (double)d[ab.x] * (double)d[ab.y];
    }
    for (int off = 32; off > 0; off >>= 1) {
      s1 += __shfl_down(s1, off);
      s2 += __shfl_down(s2, off);
      sn += __shfl_down(sn, off);
      st += __shfl_down(st, off);
    }
    s1 = __shfl(s1, 0); s2 = __shfl(s2, 0); sn = __shfl(sn, 0); st = __shfl(st, 0);
    double cross = 2.0 * (double)d0 * sn + st;
    double li = gamma - (ed + s1) + (dAd + 2.0 * s2 + cross);
    if (li <= loss) {
      if (t == 0) { selb[idx] = 1; d[idx] = 1.f; }
      for (int e = r0 + t; e < r1; e += 64) { int j = col[e]; rejb[j] = 1; d[j] = 0.f; }
      __syncthreads();
      float dai = del[idx];
      for (int e = r0 + t; e < r1; e += 64) atomicAdd(&q[col[e]], dai);
      for (int ee = r0; ee < r1; ++ee) {
        int a = col[ee];
        float da = del[a];
        if (da != 0.f) {
          int a0 = rp[a], a1 = rp[a + 1];
          for (int e = a0 + t; e < a1; e += 64) atomicAdd(&q[col[e]], da);
        }
      }
      ed += s1; dAd += 2.0 * s2 + cross;
      __syncthreads();
    }
    if (t == 0) del[idx] = 0.f;
    for (int e = r0 + t; e < r1; e += 64) del[col[e]] = 0.f;
    __syncthreads();
  }
  for (int i = t; i < NN; i += 64) selb_g[i] = selb[i];
}

// ---------------- boolean A^2 / A^3 ----------------
__global__ void k_reach(const u64* __restrict__ src, const int* __restrict__ rp,
                        const int* __restrict__ col, u64* __restrict__ dst) {
  int node = blockIdx.x * 2 + (threadIdx.x >> 5);
  int w = threadIdx.x & 31;
  u64 acc = 0;
  for (int e = rp[node]; e < rp[node + 1]; ++e) acc |= src[((size_t)col[e] << 5) + w];
  dst[((size_t)node << 5) + w] = acc;
}

// ---------------- outputs ----------------
__global__ void k_outA(const u64* __restrict__ row2, const u64* __restrict__ row3,
                       const u8* __restrict__ selb, float* __restrict__ adj) {
  int idx = blockIdx.x * blockDim.x + threadIdx.x; // NN*NN
  int i = idx >> 11, j = idx & 2047;
  int wo = (i << 5) + (j >> 6);
  u64 b = (row2[wo] | row3[wo]) >> (j & 63);
  adj[idx] = ((b & 1ull) && i != j && selb[i] && selb[j]) ? 1.f : 0.f;
}

__global__ void k_outX(const float* __restrict__ x, const u8* __restrict__ selb,
                       float* __restrict__ xo) {
  int idx = blockIdx.x * blockDim.x + threadIdx.x; // NN*DIMF
  int i = idx >> 8;
  xo[idx] = selb[i] ? x[idx] : 0.f;
}

__global__ void k_outS(const u8* __restrict__ selb, const int* __restrict__ batch,
                       const double* __restrict__ scal, float* __restrict__ osel,
                       float* __restrict__ obatch, float* __restrict__ oloss) {
  int i = blockIdx.x * blockDim.x + threadIdx.x;
  if (i < NN) {
    osel[i] = selb[i] ? 1.f : 0.f;
    obatch[i] = selb[i] ? (float)batch[i] : -1.f;
  }
  if (i == 0) oloss[0] = (float)scal[3];
}

extern "C" void kernel_launch(void* const* d_in, const int* in_sizes, int n_in,
                              void* d_out, int out_size, void* d_ws, size_t ws_size,
                              hipStream_t stream) {
  const float* x    = (const float*)d_in[0];
  const int*   ei   = (const int*)d_in[1];
  const int*   batch= (const int*)d_in[2];
  const float* w11  = (const float*)d_in[3];
  const float* b11  = (const float*)d_in[4];
  const float* g1   = (const float*)d_in[5];
  const float* be1  = (const float*)d_in[6];
  const float* w12  = (const float*)d_in[7];
  const float* b12  = (const float*)d_in[8];
  const float* w21  = (const float*)d_in[9];
  const float* b21  = (const float*)d_in[10];
  const float* g2   = (const float*)d_in[11];
  const float* be2  = (const float*)d_in[12];
  const float* w22  = (const float*)d_in[13];
  const float* b22  = (const float*)d_in[14];
  const float* w31  = (const float*)d_in[15];
  const float* b31  = (const float*)d_in[16];
  const float* g3   = (const float*)d_in[17];
  const float* be3  = (const float*)d_in[18];
  const float* w32  = (const float*)d_in[19];
  const float* b32  = (const float*)d_in[20];

  char* wsb = (char*)d_ws;
  size_t cur = 0;
  auto alloc = [&](size_t bytes) -> void* {
    void* pp = wsb + cur;
    cur += (bytes + 255) & ~(size_t)255;
    return pp;
  };
  u64*    rowbits = (u64*)alloc((size_t)NN * W32 * 8);
  u64*    row2    = (u64*)alloc((size_t)NN * W32 * 8);
  u64*    row3    = (u64*)alloc((size_t)NN * W32 * 8);
  u64*    keys    = (u64*)alloc((size_t)NN * 8);
  double* seggam  = (double*)alloc(NG * 8);
  double* scal    = (double*)alloc(4 * 8);
  int*    deg     = (int*)alloc(NN * 4);
  int*    rowptr  = (int*)alloc((NN + 1) * 4);
  int*    colx    = (int*)alloc(65536 * 4);
  int*    tricnt  = (int*)alloc(NN * 4);
  int*    triptr  = (int*)alloc((NN + 1) * 4);
  int2*   tri     = (int2*)alloc((size_t)TRI_CAP * 8);
  int*    segst   = (int*)alloc((NG + 1) * 4);
  int*    order   = (int*)alloc(NN * 4);
  float*  ent     = (float*)alloc(NN * 4);
  float*  V       = (float*)alloc(NN * 4);
  float*  p       = (float*)alloc(NN * 4);
  float*  q0      = (float*)alloc(NN * 4);
  float*  agg1    = (float*)alloc(NN * 4);
  float*  scale   = (float*)alloc(HIDN * 4);
  float*  shift   = (float*)alloc(HIDN * 4);
  float*  tA      = (float*)alloc((size_t)NN * HIDN * 4);
  float*  tB      = (float*)alloc((size_t)NN * HIDN * 4);
  float*  tC      = (float*)alloc((size_t)NN * HIDN * 4);
  u8*     selb    = (u8*)alloc(NN);

  float* out    = (float*)d_out;
  float* o_x    = out;                       // 524288
  float* o_adj  = out + 524288;              // 4194304
  float* o_sel  = out + 4718592;             // 2048
  float* o_bat  = out + 4720640;             // 2048
  float* o_loss = out + 4722688;             // 1

  k_init<<<64, 256, 0, stream>>>(rowbits, segst);
  k_edges<<<128, 256, 0, stream>>>(ei, rowbits);
  k_deg<<<8, 256, 0, stream>>>(rowbits, deg);
  k_scan2048<<<1, 256, 0, stream>>>(deg, rowptr);
  k_extract<<<8, 256, 0, stream>>>(rowbits, rowptr, colx);
  k_tricnt<<<8, 256, 0, stream>>>(rowbits, rowptr, colx, tricnt);
  k_scan2048<<<1, 256, 0, stream>>>(tricnt, triptr);
  k_trifill<<<8, 256, 0, stream>>>(rowbits, rowptr, colx, triptr, tri);
  k_V<<<NN, 256, 0, stream>>>(x, rowptr, colx, V);
  k_bounds<<<8, 256, 0, stream>>>(batch, segst);
  k_soft<<<NG, 256, 0, stream>>>(V, segst, ent, seggam);

  // layer 1
  k_agg1<<<8, 256, 0, stream>>>(ent, rowptr, colx, agg1);
  k_lin1<<<1024, 256, 0, stream>>>(agg1, w11, b11, tA);
  k_bn<<<HIDN, 256, 0, stream>>>(tA, g1, be1, scale, shift);
  k_mm<1, 0><<<NN / 8, HIDN, 0, stream>>>(tA, w12, b12, scale, shift, tB);
  // layer 2
  k_agg128<<<NN, HIDN, 0, stream>>>(tB, rowptr, colx, tC);
  k_mm<0, 1><<<NN / 8, HIDN, 0, stream>>>(tC, w21, b21, scale, shift, tA);
  k_bn<<<HIDN, 256, 0, stream>>>(tA, g2, be2, scale, shift);
  k_mm<1, 0><<<NN / 8, HIDN, 0, stream>>>(tA, w22, b22, scale, shift, tB);
  // layer 3
  k_agg128<<<NN, HIDN, 0, stream>>>(tB, rowptr, colx, tC);
  k_mm<0, 1><<<NN / 8, HIDN, 0, stream>>>(tC, w31, b31, scale, shift, tA);
  k_bn<<<HIDN, 256, 0, stream>>>(tA, g3, be3, scale, shift);
  k_lin3<<<NN, HIDN, 0, stream>>>(tA, scale, shift, w32, b32, p);

  k_q0<<<8, 256, 0, stream>>>(p, rowptr, colx, q0);
  k_loss<<<1, 256, 0, stream>>>(ent, p, q0, seggam, scal);
  k_keys<<<8, 256, 0, stream>>>(p, keys);
  k_sort<<<1, 1024, 0, stream>>>(keys, order);
  k_greedy<<<1, 64, 0, stream>>>(rowptr, colx, triptr, tri, order, p, ent, q0, scal, selb);

  k_reach<<<NN / 2, 64, 0, stream>>>(rowbits, rowptr, colx, row2);
  k_reach<<<NN / 2, 64, 0, stream>>>(row2, rowptr, colx, row3);
  k_outA<<<NN * NN / 256, 256, 0, stream>>>(row2, row3, selb, o_adj);
  k_outX<<<NN * DIMF / 256, 256, 0, stream>>>(x, selb, o_x);
  k_outS<<<8, 256, 0, stream>>>(selb, batch, scal, o_sel, o_bat, o_loss);

  (void)in_sizes; (void)n_in; (void)out_size; (void)ws_size;
}

// Round 2
// 1848.109 us; speedup vs baseline: 1.2477x; 1.2477x over previous
//
#include <hip/hip_runtime.h>
#include <math.h>

#define NN 2048
#define DIMF 256
#define HIDN 128
#define NG 8
#define NEDGES 32768
#define W32 32
#define TRI_CAP 131072
#define TRI_LDS 4864

typedef unsigned long long u64;
typedef unsigned char u8;
typedef unsigned short u16;

// ---------------- build adjacency ----------------
__global__ void k_init(u64* __restrict__ rowbits, int* __restrict__ segstart) {
  int i = blockIdx.x * blockDim.x + threadIdx.x;
  for (int k = i; k < NN * W32; k += gridDim.x * blockDim.x) rowbits[k] = 0ull;
  if (i <= NG) segstart[i] = NN;
}

__global__ void k_edges(const int* __restrict__ ei, u64* __restrict__ rowbits) {
  int e = blockIdx.x * blockDim.x + threadIdx.x;
  if (e >= NEDGES) return;
  int u = ei[e], v = ei[NEDGES + e];
  atomicOr(&rowbits[((size_t)u << 5) + (v >> 6)], 1ull << (v & 63));
}

__global__ void k_deg(const u64* __restrict__ rowbits, int* __restrict__ deg) {
  int i = blockIdx.x * blockDim.x + threadIdx.x;
  if (i >= NN) return;
  int c = 0;
  for (int w = 0; w < W32; ++w) c += __popcll(rowbits[(i << 5) + w]);
  deg[i] = c;
}

// exclusive scan of 2048 ints -> out[0..2048]
__global__ void k_scan2048(const int* __restrict__ in, int* __restrict__ out) {
  __shared__ int part[256];
  int t = threadIdx.x;
  int v[8]; int s = 0;
  for (int k = 0; k < 8; ++k) { v[k] = in[t * 8 + k]; s += v[k]; }
  part[t] = s;
  __syncthreads();
  for (int off = 1; off < 256; off <<= 1) {
    int y = (t >= off) ? part[t - off] : 0;
    __syncthreads();
    part[t] += y;
    __syncthreads();
  }
  int run = part[t] - s;
  for (int k = 0; k < 8; ++k) { out[t * 8 + k] = run; run += v[k]; }
  if (t == 255) out[NN] = part[255];
}

__global__ void k_extract(const u64* __restrict__ rowbits, const int* __restrict__ rp, int* __restrict__ col) {
  int i = blockIdx.x * blockDim.x + threadIdx.x;
  if (i >= NN) return;
  int o = rp[i];
  for (int w = 0; w < W32; ++w) {
    u64 b = rowbits[(i << 5) + w];
    while (b) { col[o++] = (w << 6) + __builtin_ctzll(b); b &= b - 1; }
  }
}

// ordered triangle pairs (a,b): a,b in N(i), A_ab=1
__global__ void k_tricnt(const u64* __restrict__ rowbits, const int* __restrict__ rp,
                         const int* __restrict__ col, int* __restrict__ cnt) {
  int i = blockIdx.x * blockDim.x + threadIdx.x;
  if (i >= NN) return;
  const u64* ri = rowbits + ((size_t)i << 5);
  int c = 0;
  for (int e = rp[i]; e < rp[i + 1]; ++e) {
    const u64* ra = rowbits + ((size_t)col[e] << 5);
    for (int w = 0; w < W32; ++w) c += __popcll(ra[w] & ri[w]);
  }
  cnt[i] = c;
}

__global__ void k_trifill(const u64* __restrict__ rowbits, const int* __restrict__ rp,
                          const int* __restrict__ col, const int* __restrict__ tp,
                          int2* __restrict__ tri) {
  int i = blockIdx.x * blockDim.x + threadIdx.x;
  if (i >= NN) return;
  const u64* ri = rowbits + ((size_t)i << 5);
  int o = tp[i];
  for (int e = rp[i]; e < rp[i + 1]; ++e) {
    int a = col[e];
    const u64* ra = rowbits + ((size_t)a << 5);
    for (int w = 0; w < W32; ++w) {
      u64 b = ra[w] & ri[w];
      while (b) {
        int j = (w << 6) + __builtin_ctzll(b);
        if (o < TRI_CAP) tri[o] = make_int2(a, j);
        ++o;
        b &= b - 1;
      }
    }
  }
}

// ---------------- entropy term ----------------
__global__ void k_V(const float* __restrict__ x, const int* __restrict__ rp,
                    const int* __restrict__ col, float* __restrict__ V) {
  int i = blockIdx.x; int t = threadIdx.x; // 256 threads = dims
  float xi = x[i * DIMF + t];
  float s1 = 0.f, s2 = 0.f;
  int r0 = rp[i], r1 = rp[i + 1];
  for (int e = r0; e < r1; ++e) {
    float xj = x[col[e] * DIMF + t];
    s1 += xj; s2 += xj * xj;
  }
  float dg = (float)(r1 - r0);
  float val = dg * xi * xi - 2.f * xi * s1 + s2;
  __shared__ double red[DIMF];
  red[t] = (double)val * (double)val;
  __syncthreads();
  for (int off = DIMF / 2; off > 0; off >>= 1) { if (t < off) red[t] += red[t + off]; __syncthreads(); }
  if (t == 0) V[i] = (float)sqrt(red[0]);
}

__global__ void k_bounds(const int* __restrict__ batch, int* __restrict__ segstart) {
  int i = blockIdx.x * blockDim.x + threadIdx.x;
  if (i >= NN) return;
  if (i == 0 || batch[i] != batch[i - 1]) segstart[batch[i]] = i;
}

__global__ void k_soft(const float* __restrict__ V, const int* __restrict__ segstart,
                       float* __restrict__ ent, double* __restrict__ seggamma) {
  int g = blockIdx.x; int t = threadIdx.x;
  int s = segstart[g];
  int e = NN;
  for (int gg = g + 1; gg <= NG; ++gg) { int v = segstart[gg]; if (v < e) e = v; }
  if (s >= e) { if (t == 0) seggamma[g] = 0.0; return; }
  __shared__ float fm[256];
  __shared__ double dd[256];
  float m = -3.0e38f;
  for (int i = s + t; i < e; i += 256) m = fmaxf(m, V[i]);
  fm[t] = m; __syncthreads();
  for (int off = 128; off > 0; off >>= 1) { if (t < off) fm[t] = fmaxf(fm[t], fm[t + off]); __syncthreads(); }
  float mx = fm[0];
  __syncthreads();
  double sum = 0.0;
  for (int i = s + t; i < e; i += 256) sum += exp((double)V[i] - (double)mx);
  dd[t] = sum; __syncthreads();
  for (int off = 128; off > 0; off >>= 1) { if (t < off) dd[t] += dd[t + off]; __syncthreads(); }
  double tot = dd[0];
  __syncthreads();
  double gs = 0.0;
  for (int i = s + t; i < e; i += 256) {
    double P = exp((double)V[i] - (double)mx) / tot;
    float ev = (P > 0.0) ? (float)(-P * log(P)) : 0.f;
    ent[i] = ev;
    gs += (double)ev;
  }
  dd[t] = gs; __syncthreads();
  for (int off = 128; off > 0; off >>= 1) { if (t < off) dd[t] += dd[t + off]; __syncthreads(); }
  if (t == 0) seggamma[g] = dd[0];
}

// ---------------- GIN MLPs ----------------
__global__ void k_agg1(const float* __restrict__ ent, const int* __restrict__ rp,
                       const int* __restrict__ col, float* __restrict__ agg) {
  int i = blockIdx.x * blockDim.x + threadIdx.x;
  if (i >= NN) return;
  float a = ent[i];
  for (int e = rp[i]; e < rp[i + 1]; ++e) a += ent[col[e]];
  agg[i] = a;
}

__global__ void k_lin1(const float* __restrict__ agg, const float* __restrict__ w,
                       const float* __restrict__ b, float* __restrict__ t) {
  int idx = blockIdx.x * blockDim.x + threadIdx.x;
  if (idx >= NN * HIDN) return;
  int i = idx >> 7, k = idx & 127;
  float v = agg[i] * w[k] + b[k];
  t[idx] = v > 0.f ? v : 0.f;
}

__global__ void k_bn(const float* __restrict__ t, const float* __restrict__ g,
                     const float* __restrict__ be, float* __restrict__ scale,
                     float* __restrict__ shift) {
  int k = blockIdx.x; int tid = threadIdx.x; // 256 threads per column
  __shared__ double red[256];
  double s = 0.0;
  for (int i = tid; i < NN; i += 256) s += (double)t[i * HIDN + k];
  red[tid] = s; __syncthreads();
  for (int off = 128; off > 0; off >>= 1) { if (tid < off) red[tid] += red[tid + off]; __syncthreads(); }
  double mu = red[0] / NN;
  __syncthreads();
  double v = 0.0;
  for (int i = tid; i < NN; i += 256) { double dv = (double)t[i * HIDN + k] - mu; v += dv * dv; }
  red[tid] = v; __syncthreads();
  for (int off = 128; off > 0; off >>= 1) { if (tid < off) red[tid] += red[tid + off]; __syncthreads(); }
  if (tid == 0) {
    float var = (float)(red[0] / NN);
    float sc = g[k] / sqrtf(var + 1e-5f);
    scale[k] = sc;
    shift[k] = be[k] - (float)mu * sc;
  }
}

template<int PRE, int RELU>
__global__ void k_mm(const float* __restrict__ in, const float* __restrict__ Wm,
                     const float* __restrict__ bias, const float* __restrict__ scale,
                     const float* __restrict__ shift, float* __restrict__ out) {
  __shared__ float ti[8][HIDN];
  int r0 = blockIdx.x * 8; int t = threadIdx.x; // 128 threads
  for (int r = 0; r < 8; ++r) {
    float v = in[(r0 + r) * HIDN + t];
    if (PRE) v = v * scale[t] + shift[t];
    ti[r][t] = v;
  }
  __syncthreads();
  float acc[8];
  #pragma unroll
  for (int r = 0; r < 8; ++r) acc[r] = 0.f;
  for (int k = 0; k < HIDN; ++k) {
    float w = Wm[k * HIDN + t];
    #pragma unroll
    for (int r = 0; r < 8; ++r) acc[r] += ti[r][k] * w;
  }
  for (int r = 0; r < 8; ++r) {
    float v = acc[r] + bias[t];
    if (RELU) v = fmaxf(v, 0.f);
    out[(r0 + r) * HIDN + t] = v;
  }
}

__global__ void k_agg128(const float* __restrict__ h, const int* __restrict__ rp,
                         const int* __restrict__ col, float* __restrict__ agg) {
  int i = blockIdx.x; int t = threadIdx.x; // 128 threads
  float a = h[i * HIDN + t];
  for (int e = rp[i]; e < rp[i + 1]; ++e) a += h[col[e] * HIDN + t];
  agg[i * HIDN + t] = a;
}

__global__ void k_lin3(const float* __restrict__ tn, const float* __restrict__ scale,
                       const float* __restrict__ shift, const float* __restrict__ w32,
                       const float* __restrict__ b32, float* __restrict__ p) {
  int i = blockIdx.x; int t = threadIdx.x; // 128
  float v = (tn[i * HIDN + t] * scale[t] + shift[t]) * w32[t];
  __shared__ float red[HIDN];
  red[t] = v; __syncthreads();
  for (int off = 64; off > 0; off >>= 1) { if (t < off) red[t] += red[t + off]; __syncthreads(); }
  if (t == 0) {
    float h3 = red[0] + b32[0];
    p[i] = 1.f / (1.f + expf(-h3));
  }
}

// ---------------- loss ----------------
__global__ void k_q0(const float* __restrict__ p, const int* __restrict__ rp,
                     const int* __restrict__ col, float* __restrict__ q0) {
  int i = blockIdx.x * blockDim.x + threadIdx.x;
  if (i >= NN) return;
  float s = 0.f;
  for (int e = rp[i]; e < rp[i + 1]; ++e) s += p[col[e]];
  q0[i] = s;
}

__global__ void k_loss(const float* __restrict__ ent, const float* __restrict__ p,
                       const float* __restrict__ q0, const double* __restrict__ seggamma,
                       double* __restrict__ scal) {
  __shared__ double ra[256], rb[256];
  int t = threadIdx.x;
  double a = 0.0, b = 0.0;
  for (int i = t; i < NN; i += 256) { a += (double)ent[i] * (double)p[i]; b += (double)p[i] * (double)q0[i]; }
  ra[t] = a; rb[t] = b; __syncthreads();
  for (int off = 128; off > 0; off >>= 1) {
    if (t < off) { ra[t] += ra[t + off]; rb[t] += rb[t + off]; }
    __syncthreads();
  }
  if (t == 0) {
    double gamma = 0.0;
    for (int g = 0; g < NG; ++g) gamma += seggamma[g];
    scal[0] = gamma; scal[1] = ra[0]; scal[2] = rb[0];
    scal[3] = gamma - ra[0] + rb[0];
  }
}

// ---------------- sort (descending p, stable) ----------------
__global__ void k_keys(const float* __restrict__ p, u64* __restrict__ keys) {
  int i = blockIdx.x * blockDim.x + threadIdx.x;
  if (i >= NN) return;
  unsigned int b = __float_as_uint(p[i]);
  unsigned int s = (b & 0x80000000u) ? ~b : (b | 0x80000000u);
  keys[i] = ((u64)(~s) << 32) | (unsigned int)i;
}

__global__ void k_sort(const u64* __restrict__ keys, int* __restrict__ order) {
  __shared__ u64 s[NN];
  int t = threadIdx.x; // 1024
  s[t] = keys[t]; s[t + 1024] = keys[t + 1024];
  __syncthreads();
  for (int k = 2; k <= NN; k <<= 1) {
    for (int j = k >> 1; j > 0; j >>= 1) {
      for (int i = t; i < NN; i += 1024) {
        int ixj = i ^ j;
        if (ixj > i) {
          bool up = ((i & k) == 0);
          u64 a = s[i], b = s[ixj];
          if ((a > b) == up) { s[i] = b; s[ixj] = a; }
        }
      }
      __syncthreads();
    }
  }
  order[t] = (int)(s[t] & 0xFFFFFFFFull);
  order[t + 1024] = (int)(s[t + 1024] & 0xFFFFFFFFull);
}

// ---------------- greedy sequential selection (1 wave, all state in LDS) ----------------
struct NodeF { float d, q, ent, pad; };

__global__ void __launch_bounds__(64) k_greedy(
    const int* __restrict__ rp, const int* __restrict__ col,
    const int* __restrict__ tp, const int2* __restrict__ tri,
    const int* __restrict__ order, const float* __restrict__ p,
    const float* __restrict__ ent, const float* __restrict__ q0,
    const double* __restrict__ scal, u8* __restrict__ selb_g) {
  __shared__ NodeF nd[NN];            // 32 KB: d, q, ent packed (one b128 per neighbor)
  __shared__ u16 colL[NEDGES];        // 64 KB
  __shared__ u16 ordl[NN];            // 4 KB
  __shared__ u16 rpL[NN + 2];         // rp[NN] <= 32768 fits u16
  __shared__ u16 tpL[NN + 2];         // clamped to 65535
  __shared__ ushort2 triL[TRI_LDS];   // 19 KB triangle-pair cache
  __shared__ unsigned selw[64], rejw[64];
  int t = threadIdx.x;
  for (int i = t; i < NN; i += 64) {
    NodeF v; v.d = p[i]; v.q = q0[i]; v.ent = ent[i]; v.pad = 0.f;
    nd[i] = v;
    ordl[i] = (u16)order[i];
    rpL[i] = (u16)rp[i];
    int tv = tp[i]; tpL[i] = (u16)(tv > 65535 ? 65535 : tv);
  }
  if (t == 0) {
    rpL[NN] = (u16)rp[NN];
    int tv = tp[NN]; tpL[NN] = (u16)(tv > 65535 ? 65535 : tv);
  }
  for (int i = t; i < NEDGES; i += 64) colL[i] = (u16)col[i];
  for (int i = t; i < TRI_LDS; i += 64) {
    int2 ab = tri[i];
    triL[i] = make_ushort2((u16)(ab.x & 2047), (u16)(ab.y & 2047));
  }
  if (t < 64) { selw[t] = 0u; rejw[t] = 0u; }
  double gamma = scal[0], ed = scal[1], dAd = scal[2], loss = scal[3];
  __syncthreads();

  for (int step = 0; step < NN; ++step) {
    int idx = ordl[step];
    int r0 = rpL[idx], r1 = rpL[idx + 1];
    if (r1 == r0) {  // isolated -> selected, no state change
      if (t == 0) selw[idx >> 5] |= (1u << (idx & 31));
      continue;
    }
    unsigned decided = (selw[idx >> 5] | rejw[idx >> 5]) >> (idx & 31);
    if (decided & 1u) continue;

    float s1 = 0.f, s2 = 0.f, sn = 0.f, st = 0.f;
    for (int e = r0 + t; e < r1; e += 64) {
      int j = colL[e];
      NodeF v = nd[j];
      s1 -= v.ent * v.d;
      s2 -= v.q * v.d;
      sn -= v.d;
    }
    NodeF vi = nd[idx];  // broadcast read
    float d0 = 1.f - vi.d;
    if (t == 0) { s1 += vi.ent * d0; s2 += vi.q * d0; }
    int t0 = tpL[idx], t1 = tpL[idx + 1];
    if (t1 <= TRI_LDS) {
      for (int e = t0 + t; e < t1; e += 64) {
        ushort2 ab = triL[e];
        st += nd[ab.x].d * nd[ab.y].d;
      }
    } else {  // rare overflow: true offsets + pairs from global
      int g0 = tp[idx], g1 = tp[idx + 1];
      if (g1 > TRI_CAP) g1 = TRI_CAP;
      if (g0 > TRI_CAP) g0 = TRI_CAP;
      for (int e = g0 + t; e < g1; e += 64) {
        int2 ab = tri[e];
        st += nd[ab.x].d * nd[ab.y].d;
      }
    }
    #pragma unroll
    for (int off = 1; off < 64; off <<= 1) {
      s1 += __shfl_xor(s1, off);
      s2 += __shfl_xor(s2, off);
      sn += __shfl_xor(sn, off);
      st += __shfl_xor(st, off);
    }
    double cross = 2.0 * (double)d0 * (double)sn + (double)st;
    double li = gamma - (ed + (double)s1) + (dAd + 2.0 * (double)s2 + cross);
    if (li <= loss) {
      // q updates use OLD d values (d not yet modified)
      float dai = d0;
      for (int e = r0 + t; e < r1; e += 64) atomicAdd(&nd[colL[e]].q, dai);
      for (int ee = r0; ee < r1; ++ee) {
        int a = colL[ee];
        float da = -nd[a].d;
        if (da != 0.f) {
          int a0 = rpL[a], a1 = rpL[a + 1];
          for (int e = a0 + t; e < a1; e += 64) atomicAdd(&nd[colL[e]].q, da);
        }
      }
      __syncthreads();  // single wave: compiles to lgkmcnt drain
      if (t == 0) { selw[idx >> 5] |= (1u << (idx & 31)); nd[idx].d = 1.f; }
      for (int e = r0 + t; e < r1; e += 64) {
        int j = colL[e];
        atomicOr(&rejw[j >> 5], 1u << (j & 31));
        nd[j].d = 0.f;
      }
      ed += (double)s1;
      dAd += 2.0 * (double)s2 + cross;
      __syncthreads();
    }
  }
  for (int i = t; i < NN; i += 64)
    selb_g[i] = (u8)((selw[i >> 5] >> (i & 31)) & 1u);
}

// ---------------- boolean A^2 / A^3 ----------------
__global__ void k_reach(const u64* __restrict__ src, const int* __restrict__ rp,
                        const int* __restrict__ col, u64* __restrict__ dst) {
  int node = blockIdx.x * 2 + (threadIdx.x >> 5);
  int w = threadIdx.x & 31;
  u64 acc = 0;
  for (int e = rp[node]; e < rp[node + 1]; ++e) acc |= src[((size_t)col[e] << 5) + w];
  dst[((size_t)node << 5) + w] = acc;
}

// ---------------- outputs ----------------
__global__ void k_outA(const u64* __restrict__ row2, const u64* __restrict__ row3,
                       const u8* __restrict__ selb, float* __restrict__ adj) {
  int idx = blockIdx.x * blockDim.x + threadIdx.x; // NN*NN
  int i = idx >> 11, j = idx & 2047;
  int wo = (i << 5) + (j >> 6);
  u64 b = (row2[wo] | row3[wo]) >> (j & 63);
  adj[idx] = ((b & 1ull) && i != j && selb[i] && selb[j]) ? 1.f : 0.f;
}

__global__ void k_outX(const float* __restrict__ x, const u8* __restrict__ selb,
                       float* __restrict__ xo) {
  int idx = blockIdx.x * blockDim.x + threadIdx.x; // NN*DIMF
  int i = idx >> 8;
  xo[idx] = selb[i] ? x[idx] : 0.f;
}

__global__ void k_outS(const u8* __restrict__ selb, const int* __restrict__ batch,
                       const double* __restrict__ scal, float* __restrict__ osel,
                       float* __restrict__ obatch, float* __restrict__ oloss) {
  int i = blockIdx.x * blockDim.x + threadIdx.x;
  if (i < NN) {
    osel[i] = selb[i] ? 1.f : 0.f;
    obatch[i] = selb[i] ? (float)batch[i] : -1.f;
  }
  if (i == 0) oloss[0] = (float)scal[3];
}

extern "C" void kernel_launch(void* const* d_in, const int* in_sizes, int n_in,
                              void* d_out, int out_size, void* d_ws, size_t ws_size,
                              hipStream_t stream) {
  const float* x    = (const float*)d_in[0];
  const int*   ei   = (const int*)d_in[1];
  const int*   batch= (const int*)d_in[2];
  const float* w11  = (const float*)d_in[3];
  const float* b11  = (const float*)d_in[4];
  const float* g1   = (const float*)d_in[5];
  const float* be1  = (const float*)d_in[6];
  const float* w12  = (const float*)d_in[7];
  const float* b12  = (const float*)d_in[8];
  const float* w21  = (const float*)d_in[9];
  const float* b21  = (const float*)d_in[10];
  const float* g2   = (const float*)d_in[11];
  const float* be2  = (const float*)d_in[12];
  const float* w22  = (const float*)d_in[13];
  const float* b22  = (const float*)d_in[14];
  const float* w31  = (const float*)d_in[15];
  const float* b31  = (const float*)d_in[16];
  const float* g3   = (const float*)d_in[17];
  const float* be3  = (const float*)d_in[18];
  const float* w32  = (const float*)d_in[19];
  const float* b32  = (const float*)d_in[20];

  char* wsb = (char*)d_ws;
  size_t cur = 0;
  auto alloc = [&](size_t bytes) -> void* {
    void* pp = wsb + cur;
    cur += (bytes + 255) & ~(size_t)255;
    return pp;
  };
  u64*    rowbits = (u64*)alloc((size_t)NN * W32 * 8);
  u64*    row2    = (u64*)alloc((size_t)NN * W32 * 8);
  u64*    row3    = (u64*)alloc((size_t)NN * W32 * 8);
  u64*    keys    = (u64*)alloc((size_t)NN * 8);
  double* seggam  = (double*)alloc(NG * 8);
  double* scal    = (double*)alloc(4 * 8);
  int*    deg     = (int*)alloc(NN * 4);
  int*    rowptr  = (int*)alloc((NN + 1) * 4);
  int*    colx    = (int*)alloc(65536 * 4);
  int*    tricnt  = (int*)alloc(NN * 4);
  int*    triptr  = (int*)alloc((NN + 1) * 4);
  int2*   tri     = (int2*)alloc((size_t)TRI_CAP * 8);
  int*    segst   = (int*)alloc((NG + 1) * 4);
  int*    order   = (int*)alloc(NN * 4);
  float*  ent     = (float*)alloc(NN * 4);
  float*  V       = (float*)alloc(NN * 4);
  float*  p       = (float*)alloc(NN * 4);
  float*  q0      = (float*)alloc(NN * 4);
  float*  agg1    = (float*)alloc(NN * 4);
  float*  scale   = (float*)alloc(HIDN * 4);
  float*  shift   = (float*)alloc(HIDN * 4);
  float*  tA      = (float*)alloc((size_t)NN * HIDN * 4);
  float*  tB      = (float*)alloc((size_t)NN * HIDN * 4);
  float*  tC      = (float*)alloc((size_t)NN * HIDN * 4);
  u8*     selb    = (u8*)alloc(NN);

  float* out    = (float*)d_out;
  float* o_x    = out;                       // 524288
  float* o_adj  = out + 524288;              // 4194304
  float* o_sel  = out + 4718592;             // 2048
  float* o_bat  = out + 4720640;             // 2048
  float* o_loss = out + 4722688;             // 1

  k_init<<<64, 256, 0, stream>>>(rowbits, segst);
  k_edges<<<128, 256, 0, stream>>>(ei, rowbits);
  k_deg<<<8, 256, 0, stream>>>(rowbits, deg);
  k_scan2048<<<1, 256, 0, stream>>>(deg, rowptr);
  k_extract<<<8, 256, 0, stream>>>(rowbits, rowptr, colx);
  k_tricnt<<<8, 256, 0, stream>>>(rowbits, rowptr, colx, tricnt);
  k_scan2048<<<1, 256, 0, stream>>>(tricnt, triptr);
  k_trifill<<<8, 256, 0, stream>>>(rowbits, rowptr, colx, triptr, tri);
  k_V<<<NN, 256, 0, stream>>>(x, rowptr, colx, V);
  k_bounds<<<8, 256, 0, stream>>>(batch, segst);
  k_soft<<<NG, 256, 0, stream>>>(V, segst, ent, seggam);

  // layer 1
  k_agg1<<<8, 256, 0, stream>>>(ent, rowptr, colx, agg1);
  k_lin1<<<1024, 256, 0, stream>>>(agg1, w11, b11, tA);
  k_bn<<<HIDN, 256, 0, stream>>>(tA, g1, be1, scale, shift);
  k_mm<1, 0><<<NN / 8, HIDN, 0, stream>>>(tA, w12, b12, scale, shift, tB);
  // layer 2
  k_agg128<<<NN, HIDN, 0, stream>>>(tB, rowptr, colx, tC);
  k_mm<0, 1><<<NN / 8, HIDN, 0, stream>>>(tC, w21, b21, scale, shift, tA);
  k_bn<<<HIDN, 256, 0, stream>>>(tA, g2, be2, scale, shift);
  k_mm<1, 0><<<NN / 8, HIDN, 0, stream>>>(tA, w22, b22, scale, shift, tB);
  // layer 3
  k_agg128<<<NN, HIDN, 0, stream>>>(tB, rowptr, colx, tC);
  k_mm<0, 1><<<NN / 8, HIDN, 0, stream>>>(tC, w31, b31, scale, shift, tA);
  k_bn<<<HIDN, 256, 0, stream>>>(tA, g3, be3, scale, shift);
  k_lin3<<<NN, HIDN, 0, stream>>>(tA, scale, shift, w32, b32, p);

  k_q0<<<8, 256, 0, stream>>>(p, rowptr, colx, q0);
  k_loss<<<1, 256, 0, stream>>>(ent, p, q0, seggam, scal);
  k_keys<<<8, 256, 0, stream>>>(p, keys);
  k_sort<<<1, 1024, 0, stream>>>(keys, order);
  k_greedy<<<1, 64, 0, stream>>>(rowptr, colx, triptr, tri, order, p, ent, q0, scal, selb);

  k_reach<<<NN / 2, 64, 0, stream>>>(rowbits, rowptr, colx, row2);
  k_reach<<<NN / 2, 64, 0, stream>>>(row2, rowptr, colx, row3);
  k_outA<<<NN * NN / 256, 256, 0, stream>>>(row2, row3, selb, o_adj);
  k_outX<<<NN * DIMF / 256, 256, 0, stream>>>(x, selb, o_x);
  k_outS<<<8, 256, 0, stream>>>(selb, batch, scal, o_sel, o_bat, o_loss);

  (void)in_sizes; (void)n_in; (void)out_size; (void)ws_size;
}

// Round 3
// 1506.801 us; speedup vs baseline: 1.5303x; 1.2265x over previous
//
#include <hip/hip_runtime.h>
#include <math.h>

#define NN 2048
#define DIMF 256
#define HIDN 128
#define NG 8
#define NEDGES 32768
#define W32 32
#define TRI_CAP 131072
#define TRI_LDS 4864

typedef unsigned long long u64;
typedef unsigned char u8;
typedef unsigned short u16;

// ---------------- build adjacency ----------------
__global__ void k_init(u64* __restrict__ rowbits, int* __restrict__ segstart) {
  int i = blockIdx.x * blockDim.x + threadIdx.x;
  for (int k = i; k < NN * W32; k += gridDim.x * blockDim.x) rowbits[k] = 0ull;
  if (i <= NG) segstart[i] = NN;
}

__global__ void k_edges(const int* __restrict__ ei, u64* __restrict__ rowbits) {
  int e = blockIdx.x * blockDim.x + threadIdx.x;
  if (e >= NEDGES) return;
  int u = ei[e], v = ei[NEDGES + e];
  atomicOr(&rowbits[((size_t)u << 5) + (v >> 6)], 1ull << (v & 63));
}

// deg + segment bounds (fused)
__global__ void k_deg(const u64* __restrict__ rowbits, int* __restrict__ deg,
                      const int* __restrict__ batch, int* __restrict__ segstart) {
  int i = blockIdx.x * blockDim.x + threadIdx.x;
  if (i >= NN) return;
  int c = 0;
  for (int w = 0; w < W32; ++w) c += __popcll(rowbits[(i << 5) + w]);
  deg[i] = c;
  if (i == 0 || batch[i] != batch[i - 1]) segstart[batch[i]] = i;
}

// exclusive scan of 2048 ints -> out[0..2048]
__global__ void k_scan2048(const int* __restrict__ in, int* __restrict__ out) {
  __shared__ int part[256];
  int t = threadIdx.x;
  int v[8]; int s = 0;
  for (int k = 0; k < 8; ++k) { v[k] = in[t * 8 + k]; s += v[k]; }
  part[t] = s;
  __syncthreads();
  for (int off = 1; off < 256; off <<= 1) {
    int y = (t >= off) ? part[t - off] : 0;
    __syncthreads();
    part[t] += y;
    __syncthreads();
  }
  int run = part[t] - s;
  for (int k = 0; k < 8; ++k) { out[t * 8 + k] = run; run += v[k]; }
  if (t == 255) out[NN] = part[255];
}

// extract CSR + count triangle pairs (fused: tricnt uses this node's own col list)
__global__ void k_extract(const u64* __restrict__ rowbits, const int* __restrict__ rp,
                          int* __restrict__ col, int* __restrict__ cnt) {
  int i = blockIdx.x * blockDim.x + threadIdx.x;
  if (i >= NN) return;
  const u64* ri = rowbits + ((size_t)i << 5);
  int o = rp[i];
  for (int w = 0; w < W32; ++w) {
    u64 b = ri[w];
    while (b) { col[o++] = (w << 6) + __builtin_ctzll(b); b &= b - 1; }
  }
  int c = 0;
  for (int e = rp[i]; e < o; ++e) {
    const u64* ra = rowbits + ((size_t)col[e] << 5);
    for (int w = 0; w < W32; ++w) c += __popcll(ra[w] & ri[w]);
  }
  cnt[i] = c;
}

__global__ void k_trifill(const u64* __restrict__ rowbits, const int* __restrict__ rp,
                          const int* __restrict__ col, const int* __restrict__ tp,
                          int2* __restrict__ tri) {
  int i = blockIdx.x * blockDim.x + threadIdx.x;
  if (i >= NN) return;
  const u64* ri = rowbits + ((size_t)i << 5);
  int o = tp[i];
  for (int e = rp[i]; e < rp[i + 1]; ++e) {
    int a = col[e];
    const u64* ra = rowbits + ((size_t)a << 5);
    for (int w = 0; w < W32; ++w) {
      u64 b = ra[w] & ri[w];
      while (b) {
        int j = (w << 6) + __builtin_ctzll(b);
        if (o < TRI_CAP) tri[o] = make_int2(a, j);
        ++o;
        b &= b - 1;
      }
    }
  }
}

// ---------------- entropy term ----------------
__global__ void k_V(const float* __restrict__ x, const int* __restrict__ rp,
                    const int* __restrict__ col, float* __restrict__ V) {
  int i = blockIdx.x; int t = threadIdx.x; // 256 threads = dims
  float xi = x[i * DIMF + t];
  float s1 = 0.f, s2 = 0.f;
  int r0 = rp[i], r1 = rp[i + 1];
  for (int e = r0; e < r1; ++e) {
    float xj = x[col[e] * DIMF + t];
    s1 += xj; s2 += xj * xj;
  }
  float dg = (float)(r1 - r0);
  float val = dg * xi * xi - 2.f * xi * s1 + s2;
  __shared__ double red[DIMF];
  red[t] = (double)val * (double)val;
  __syncthreads();
  for (int off = DIMF / 2; off > 0; off >>= 1) { if (t < off) red[t] += red[t + off]; __syncthreads(); }
  if (t == 0) V[i] = (float)sqrt(red[0]);
}

__global__ void k_soft(const float* __restrict__ V, const int* __restrict__ segstart,
                       float* __restrict__ ent, double* __restrict__ seggamma) {
  int g = blockIdx.x; int t = threadIdx.x;
  int s = segstart[g];
  int e = NN;
  for (int gg = g + 1; gg <= NG; ++gg) { int v = segstart[gg]; if (v < e) e = v; }
  if (s >= e) { if (t == 0) seggamma[g] = 0.0; return; }
  __shared__ float fm[256];
  __shared__ double dd[256];
  float m = -3.0e38f;
  for (int i = s + t; i < e; i += 256) m = fmaxf(m, V[i]);
  fm[t] = m; __syncthreads();
  for (int off = 128; off > 0; off >>= 1) { if (t < off) fm[t] = fmaxf(fm[t], fm[t + off]); __syncthreads(); }
  float mx = fm[0];
  __syncthreads();
  double sum = 0.0;
  for (int i = s + t; i < e; i += 256) sum += exp((double)V[i] - (double)mx);
  dd[t] = sum; __syncthreads();
  for (int off = 128; off > 0; off >>= 1) { if (t < off) dd[t] += dd[t + off]; __syncthreads(); }
  double tot = dd[0];
  __syncthreads();
  double gs = 0.0;
  for (int i = s + t; i < e; i += 256) {
    double P = exp((double)V[i] - (double)mx) / tot;
    float ev = (P > 0.0) ? (float)(-P * log(P)) : 0.f;
    ent[i] = ev;
    gs += (double)ev;
  }
  dd[t] = gs; __syncthreads();
  for (int off = 128; off > 0; off >>= 1) { if (t < off) dd[t] += dd[t + off]; __syncthreads(); }
  if (t == 0) seggamma[g] = dd[0];
}

// ---------------- GIN MLPs ----------------
__global__ void k_agg1(const float* __restrict__ ent, const int* __restrict__ rp,
                       const int* __restrict__ col, float* __restrict__ agg) {
  int i = blockIdx.x * blockDim.x + threadIdx.x;
  if (i >= NN) return;
  float a = ent[i];
  for (int e = rp[i]; e < rp[i + 1]; ++e) a += ent[col[e]];
  agg[i] = a;
}

__global__ void k_lin1(const float* __restrict__ agg, const float* __restrict__ w,
                       const float* __restrict__ b, float* __restrict__ t) {
  int idx = blockIdx.x * blockDim.x + threadIdx.x;
  if (idx >= NN * HIDN) return;
  int i = idx >> 7, k = idx & 127;
  float v = agg[i] * w[k] + b[k];
  t[idx] = v > 0.f ? v : 0.f;
}

__global__ void k_bn(const float* __restrict__ t, const float* __restrict__ g,
                     const float* __restrict__ be, float* __restrict__ scale,
                     float* __restrict__ shift) {
  int k = blockIdx.x; int tid = threadIdx.x; // 256 threads per column
  __shared__ double red[256];
  double s = 0.0;
  for (int i = tid; i < NN; i += 256) s += (double)t[i * HIDN + k];
  red[tid] = s; __syncthreads();
  for (int off = 128; off > 0; off >>= 1) { if (tid < off) red[tid] += red[tid + off]; __syncthreads(); }
  double mu = red[0] / NN;
  __syncthreads();
  double v = 0.0;
  for (int i = tid; i < NN; i += 256) { double dv = (double)t[i * HIDN + k] - mu; v += dv * dv; }
  red[tid] = v; __syncthreads();
  for (int off = 128; off > 0; off >>= 1) { if (tid < off) red[tid] += red[tid + off]; __syncthreads(); }
  if (tid == 0) {
    float var = (float)(red[0] / NN);
    float sc = g[k] / sqrtf(var + 1e-5f);
    scale[k] = sc;
    shift[k] = be[k] - (float)mu * sc;
  }
}

template<int PRE, int RELU>
__global__ void k_mm(const float* __restrict__ in, const float* __restrict__ Wm,
                     const float* __restrict__ bias, const float* __restrict__ scale,
                     const float* __restrict__ shift, float* __restrict__ out) {
  __shared__ float ti[8][HIDN];
  int r0 = blockIdx.x * 8; int t = threadIdx.x; // 128 threads
  for (int r = 0; r < 8; ++r) {
    float v = in[(r0 + r) * HIDN + t];
    if (PRE) v = v * scale[t] + shift[t];
    ti[r][t] = v;
  }
  __syncthreads();
  float acc[8];
  #pragma unroll
  for (int r = 0; r < 8; ++r) acc[r] = 0.f;
  for (int k = 0; k < HIDN; ++k) {
    float w = Wm[k * HIDN + t];
    #pragma unroll
    for (int r = 0; r < 8; ++r) acc[r] += ti[r][k] * w;
  }
  for (int r = 0; r < 8; ++r) {
    float v = acc[r] + bias[t];
    if (RELU) v = fmaxf(v, 0.f);
    out[(r0 + r) * HIDN + t] = v;
  }
}

__global__ void k_agg128(const float* __restrict__ h, const int* __restrict__ rp,
                         const int* __restrict__ col, float* __restrict__ agg) {
  int i = blockIdx.x; int t = threadIdx.x; // 128 threads
  float a = h[i * HIDN + t];
  for (int e = rp[i]; e < rp[i + 1]; ++e) a += h[col[e] * HIDN + t];
  agg[i * HIDN + t] = a;
}

__global__ void k_lin3(const float* __restrict__ tn, const float* __restrict__ scale,
                       const float* __restrict__ shift, const float* __restrict__ w32,
                       const float* __restrict__ b32, float* __restrict__ p) {
  int i = blockIdx.x; int t = threadIdx.x; // 128
  float v = (tn[i * HIDN + t] * scale[t] + shift[t]) * w32[t];
  __shared__ float red[HIDN];
  red[t] = v; __syncthreads();
  for (int off = 64; off > 0; off >>= 1) { if (t < off) red[t] += red[t + off]; __syncthreads(); }
  if (t == 0) {
    float h3 = red[0] + b32[0];
    p[i] = 1.f / (1.f + expf(-h3));
  }
}

// ---------------- loss ----------------
__global__ void k_q0(const float* __restrict__ p, const int* __restrict__ rp,
                     const int* __restrict__ col, float* __restrict__ q0) {
  int i = blockIdx.x * blockDim.x + threadIdx.x;
  if (i >= NN) return;
  float s = 0.f;
  for (int e = rp[i]; e < rp[i + 1]; ++e) s += p[col[e]];
  q0[i] = s;
}

__global__ void k_loss(const float* __restrict__ ent, const float* __restrict__ p,
                       const float* __restrict__ q0, const double* __restrict__ seggamma,
                       double* __restrict__ scal) {
  __shared__ double ra[256], rb[256];
  int t = threadIdx.x;
  double a = 0.0, b = 0.0;
  for (int i = t; i < NN; i += 256) { a += (double)ent[i] * (double)p[i]; b += (double)p[i] * (double)q0[i]; }
  ra[t] = a; rb[t] = b; __syncthreads();
  for (int off = 128; off > 0; off >>= 1) {
    if (t < off) { ra[t] += ra[t + off]; rb[t] += rb[t + off]; }
    __syncthreads();
  }
  if (t == 0) {
    double gamma = 0.0;
    for (int g = 0; g < NG; ++g) gamma += seggamma[g];
    scal[0] = gamma; scal[1] = ra[0]; scal[2] = rb[0];
    scal[3] = gamma - ra[0] + rb[0];
  }
}

// ---------------- sort (descending p, stable; keys built in-kernel) ----------------
__global__ void k_sort(const float* __restrict__ p, int* __restrict__ order) {
  __shared__ u64 s[NN];
  int t = threadIdx.x; // 1024
  for (int k = t; k < NN; k += 1024) {
    unsigned b = __float_as_uint(p[k]);
    unsigned ss = (b & 0x80000000u) ? ~b : (b | 0x80000000u);
    s[k] = ((u64)(~ss) << 32) | (unsigned)k;
  }
  __syncthreads();
  for (int k = 2; k <= NN; k <<= 1) {
    for (int j = k >> 1; j > 0; j >>= 1) {
      for (int i = t; i < NN; i += 1024) {
        int ixj = i ^ j;
        if (ixj > i) {
          bool up = ((i & k) == 0);
          u64 a = s[i], b = s[ixj];
          if ((a > b) == up) { s[i] = b; s[ixj] = a; }
        }
      }
      __syncthreads();
    }
  }
  order[t] = (int)(s[t] & 0xFFFFFFFFull);
  order[t + 1024] = (int)(s[t + 1024] & 0xFFFFFFFFull);
}

// ---------------- greedy sequential selection (1 wave) ----------------
struct NodeF { float d, q, ent, pad; };

// 64-lane sum of 4 values via DPP (VALU pipe, no LDS); results broadcast to all lanes
#define DPP4(ctrl)                                                                        \
  a += __int_as_float(__builtin_amdgcn_update_dpp(0, __float_as_int(a), ctrl, 0xf, 0xf, true)); \
  b += __int_as_float(__builtin_amdgcn_update_dpp(0, __float_as_int(b), ctrl, 0xf, 0xf, true)); \
  c += __int_as_float(__builtin_amdgcn_update_dpp(0, __float_as_int(c), ctrl, 0xf, 0xf, true)); \
  d += __int_as_float(__builtin_amdgcn_update_dpp(0, __float_as_int(d), ctrl, 0xf, 0xf, true));

__device__ __forceinline__ void red4(float& a, float& b, float& c, float& d) {
  DPP4(0x111)  // row_shr:1
  DPP4(0x112)  // row_shr:2
  DPP4(0x114)  // row_shr:4
  DPP4(0x118)  // row_shr:8
  DPP4(0x142)  // row_bcast:15
  DPP4(0x143)  // row_bcast:31
  a = __int_as_float(__builtin_amdgcn_readlane(__float_as_int(a), 63));
  b = __int_as_float(__builtin_amdgcn_readlane(__float_as_int(b), 63));
  c = __int_as_float(__builtin_amdgcn_readlane(__float_as_int(c), 63));
  d = __int_as_float(__builtin_amdgcn_readlane(__float_as_int(d), 63));
}

__global__ void __launch_bounds__(64) k_greedy(
    const int* __restrict__ rp, const int* __restrict__ col,
    const int* __restrict__ tp, const int2* __restrict__ tri,
    const int* __restrict__ order, const float* __restrict__ p,
    const float* __restrict__ ent, const float* __restrict__ q0,
    const double* __restrict__ scal, u8* __restrict__ selb_g) {
  __shared__ NodeF nd[NN];            // 32 KB
  __shared__ u16 colL[NEDGES];        // 64 KB
  __shared__ u16 ordl[NN];            // 4 KB
  __shared__ unsigned rtL[NN + 2];    // 8 KB: rp | tp<<16 packed
  __shared__ ushort2 triL[TRI_LDS];   // 19 KB triangle-pair cache
  int t = threadIdx.x;
  for (int i = t; i < NN; i += 64) {
    NodeF v; v.d = p[i]; v.q = q0[i]; v.ent = ent[i]; v.pad = 0.f;
    nd[i] = v;
    ordl[i] = (u16)order[i];
    int tv = tp[i]; if (tv > 65535) tv = 65535;
    rtL[i] = (unsigned)rp[i] | ((unsigned)tv << 16);
  }
  if (t == 0) {
    int tv = tp[NN]; if (tv > 65535) tv = 65535;
    rtL[NN] = (unsigned)rp[NN] | ((unsigned)tv << 16);
  }
  for (int i = t; i < NEDGES; i += 64) colL[i] = (u16)col[i];
  for (int i = t; i < TRI_LDS; i += 64) {
    int2 ab = tri[i];
    triL[i] = make_ushort2((u16)(ab.x & 2047), (u16)(ab.y & 2047));
  }
  double gamma = scal[0], ed = scal[1], dAd = scal[2], loss = scal[3];
  __syncthreads();

  // register bitsets: lane t owns nodes [t*32, t*32+32)
  unsigned decided_v = 0u, sel_v = 0u;
  {
    int base = t * 32;
    for (int k = 0; k < 32; ++k) {
      int node = base + k;
      if (((rtL[node + 1] & 0xffffu) - (rtL[node] & 0xffffu)) == 0u) {
        decided_v |= 1u << k; sel_v |= 1u << k;  // isolated -> pre-selected
      }
    }
  }

  for (int chunk = 0; chunk < NN / 64; ++chunk) {
    int ordv = (int)ordl[chunk * 64 + t];  // 64 upcoming step indices, one per lane
    for (int s = 0; s < 64; ++s) {
      int idx = __builtin_amdgcn_readlane(ordv, s);
      unsigned w = (unsigned)__builtin_amdgcn_readlane((int)decided_v, idx >> 5);
      if ((w >> (idx & 31)) & 1u) continue;

      int w0 = __builtin_amdgcn_readfirstlane((int)rtL[idx]);
      int w1 = __builtin_amdgcn_readfirstlane((int)rtL[idx + 1]);
      int r0 = w0 & 0xffff, r1 = w1 & 0xffff;
      int t0 = (w0 >> 16) & 0xffff, t1 = (w1 >> 16) & 0xffff;
      int deg = r1 - r0;
      NodeF vi = nd[idx];  // uniform-address broadcast read

      float s1 = 0.f, s2 = 0.f, sn = 0.f, st = 0.f;
      int a_v = idx; float firstd = 0.f;
      if (t < deg) {
        a_v = (int)colL[r0 + t];
        NodeF v = nd[a_v];
        firstd = v.d;
        s1 -= v.ent * v.d; s2 -= v.q * v.d; sn -= v.d;
      }
      for (int e = r0 + t + 64; e < r1; e += 64) {
        int j = colL[e];
        NodeF v = nd[j];
        s1 -= v.ent * v.d; s2 -= v.q * v.d; sn -= v.d;
      }
      if (t1 <= TRI_LDS) {
        for (int e = t0 + t; e < t1; e += 64) {
          ushort2 ab = triL[e];
          st += nd[ab.x].d * nd[ab.y].d;
        }
      } else {  // rare overflow: true offsets + pairs from global
        int g0 = tp[idx], g1 = tp[idx + 1];
        if (g1 > TRI_CAP) g1 = TRI_CAP;
        if (g0 > TRI_CAP) g0 = TRI_CAP;
        for (int e = g0 + t; e < g1; e += 64) {
          int2 ab = tri[e];
          st += nd[ab.x].d * nd[ab.y].d;
        }
      }
      red4(s1, s2, sn, st);  // DPP VALU reduce, totals broadcast

      float d0 = 1.f - vi.d;
      float S1 = s1 + vi.ent * d0;
      float S2 = s2 + vi.q * d0;
      double cross = 2.0 * (double)d0 * (double)sn + (double)st;
      double li = gamma - (ed + (double)S1) + (dAd + 2.0 * (double)S2 + cross);
      if (li <= loss) {
        // q updates with OLD d: lane-per-neighbor scatter
        for (int l = t; l < deg; l += 64) {
          int a = (l == t) ? a_v : (int)colL[r0 + l];
          float da = (l == t) ? -firstd : -nd[a].d;
          if (da != 0.f) {
            int b0 = (int)(rtL[a] & 0xffffu), b1 = (int)(rtL[a + 1] & 0xffffu);
            for (int e = b0; e < b1; ++e)
              atomicAdd(&nd[colL[e]].q, da);
          }
        }
        for (int e = r0 + t; e < r1; e += 64)
          atomicAdd(&nd[colL[e]].q, d0);
        // d updates (reads of old d all completed above)
        for (int l = t; l < deg; l += 64) nd[colL[r0 + l]].d = 0.f;
        if (t == 0) nd[idx].d = 1.f;
        // register bitset updates: broadcast each newly-decided node
        for (int l = 0; l < deg; ++l) {
          int a = (l < 64) ? __builtin_amdgcn_readlane(a_v, l) : (int)colL[r0 + l];
          decided_v |= (t == (a >> 5)) ? (1u << (a & 31)) : 0u;
        }
        {
          unsigned m = (t == (idx >> 5)) ? (1u << (idx & 31)) : 0u;
          decided_v |= m; sel_v |= m;
        }
        ed += (double)S1;
        dAd += 2.0 * (double)S2 + cross;
        __syncthreads();  // LDS ordering paranoia (accepts are rare)
      }
    }
  }
  for (int k = 0; k < 32; ++k)
    selb_g[t * 32 + k] = (u8)((sel_v >> k) & 1u);
}

// ---------------- boolean A^2 / A^3 ----------------
__global__ void k_reach(const u64* __restrict__ src, const int* __restrict__ rp,
                        const int* __restrict__ col, u64* __restrict__ dst) {
  int node = blockIdx.x * 2 + (threadIdx.x >> 5);
  int w = threadIdx.x & 31;
  u64 acc = 0;
  for (int e = rp[node]; e < rp[node + 1]; ++e) acc |= src[((size_t)col[e] << 5) + w];
  dst[((size_t)node << 5) + w] = acc;
}

// ---------------- outputs (fused) ----------------
__global__ void k_out(const u64* __restrict__ row2, const u64* __restrict__ row3,
                      const u8* __restrict__ selb, const float* __restrict__ x,
                      const int* __restrict__ batch, const double* __restrict__ scal,
                      float* __restrict__ o_x, float* __restrict__ o_adj,
                      float* __restrict__ o_sel, float* __restrict__ o_bat,
                      float* __restrict__ o_loss) {
  int idx = blockIdx.x * blockDim.x + threadIdx.x; // NN*NN
  {
    int i = idx >> 11, j = idx & 2047;
    int wo = (i << 5) + (j >> 6);
    u64 b = (row2[wo] | row3[wo]) >> (j & 63);
    o_adj[idx] = ((b & 1ull) && i != j && selb[i] && selb[j]) ? 1.f : 0.f;
  }
  if (idx < NN * DIMF) {
    int i = idx >> 8;
    o_x[idx] = selb[i] ? x[idx] : 0.f;
  }
  if (idx < NN) {
    o_sel[idx] = selb[idx] ? 1.f : 0.f;
    o_bat[idx] = selb[idx] ? (float)batch[idx] : -1.f;
  }
  if (idx == 0) o_loss[0] = (float)scal[3];
}

extern "C" void kernel_launch(void* const* d_in, const int* in_sizes, int n_in,
                              void* d_out, int out_size, void* d_ws, size_t ws_size,
                              hipStream_t stream) {
  const float* x    = (const float*)d_in[0];
  const int*   ei   = (const int*)d_in[1];
  const int*   batch= (const int*)d_in[2];
  const float* w11  = (const float*)d_in[3];
  const float* b11  = (const float*)d_in[4];
  const float* g1   = (const float*)d_in[5];
  const float* be1  = (const float*)d_in[6];
  const float* w12  = (const float*)d_in[7];
  const float* b12  = (const float*)d_in[8];
  const float* w21  = (const float*)d_in[9];
  const float* b21  = (const float*)d_in[10];
  const float* g2   = (const float*)d_in[11];
  const float* be2  = (const float*)d_in[12];
  const float* w22  = (const float*)d_in[13];
  const float* b22  = (const float*)d_in[14];
  const float* w31  = (const float*)d_in[15];
  const float* b31  = (const float*)d_in[16];
  const float* g3   = (const float*)d_in[17];
  const float* be3  = (const float*)d_in[18];
  const float* w32  = (const float*)d_in[19];
  const float* b32  = (const float*)d_in[20];

  char* wsb = (char*)d_ws;
  size_t cur = 0;
  auto alloc = [&](size_t bytes) -> void* {
    void* pp = wsb + cur;
    cur += (bytes + 255) & ~(size_t)255;
    return pp;
  };
  u64*    rowbits = (u64*)alloc((size_t)NN * W32 * 8);
  u64*    row2    = (u64*)alloc((size_t)NN * W32 * 8);
  u64*    row3    = (u64*)alloc((size_t)NN * W32 * 8);
  double* seggam  = (double*)alloc(NG * 8);
  double* scal    = (double*)alloc(4 * 8);
  int*    deg     = (int*)alloc(NN * 4);
  int*    rowptr  = (int*)alloc((NN + 1) * 4);
  int*    colx    = (int*)alloc(65536 * 4);
  int*    tricnt  = (int*)alloc(NN * 4);
  int*    triptr  = (int*)alloc((NN + 1) * 4);
  int2*   tri     = (int2*)alloc((size_t)TRI_CAP * 8);
  int*    segst   = (int*)alloc((NG + 1) * 4);
  int*    order   = (int*)alloc(NN * 4);
  float*  ent     = (float*)alloc(NN * 4);
  float*  V       = (float*)alloc(NN * 4);
  float*  p       = (float*)alloc(NN * 4);
  float*  q0      = (float*)alloc(NN * 4);
  float*  agg1    = (float*)alloc(NN * 4);
  float*  scale   = (float*)alloc(HIDN * 4);
  float*  shift   = (float*)alloc(HIDN * 4);
  float*  tA      = (float*)alloc((size_t)NN * HIDN * 4);
  float*  tB      = (float*)alloc((size_t)NN * HIDN * 4);
  float*  tC      = (float*)alloc((size_t)NN * HIDN * 4);
  u8*     selb    = (u8*)alloc(NN);

  float* out    = (float*)d_out;
  float* o_x    = out;                       // 524288
  float* o_adj  = out + 524288;              // 4194304
  float* o_sel  = out + 4718592;             // 2048
  float* o_bat  = out + 4720640;             // 2048
  float* o_loss = out + 4722688;             // 1

  k_init<<<64, 256, 0, stream>>>(rowbits, segst);
  k_edges<<<128, 256, 0, stream>>>(ei, rowbits);
  k_deg<<<8, 256, 0, stream>>>(rowbits, deg, batch, segst);
  k_scan2048<<<1, 256, 0, stream>>>(deg, rowptr);
  k_extract<<<8, 256, 0, stream>>>(rowbits, rowptr, colx, tricnt);
  k_scan2048<<<1, 256, 0, stream>>>(tricnt, triptr);
  k_trifill<<<8, 256, 0, stream>>>(rowbits, rowptr, colx, triptr, tri);
  k_V<<<NN, 256, 0, stream>>>(x, rowptr, colx, V);
  k_soft<<<NG, 256, 0, stream>>>(V, segst, ent, seggam);

  // layer 1
  k_agg1<<<8, 256, 0, stream>>>(ent, rowptr, colx, agg1);
  k_lin1<<<1024, 256, 0, stream>>>(agg1, w11, b11, tA);
  k_bn<<<HIDN, 256, 0, stream>>>(tA, g1, be1, scale, shift);
  k_mm<1, 0><<<NN / 8, HIDN, 0, stream>>>(tA, w12, b12, scale, shift, tB);
  // layer 2
  k_agg128<<<NN, HIDN, 0, stream>>>(tB, rowptr, colx, tC);
  k_mm<0, 1><<<NN / 8, HIDN, 0, stream>>>(tC, w21, b21, scale, shift, tA);
  k_bn<<<HIDN, 256, 0, stream>>>(tA, g2, be2, scale, shift);
  k_mm<1, 0><<<NN / 8, HIDN, 0, stream>>>(tA, w22, b22, scale, shift, tB);
  // layer 3
  k_agg128<<<NN, HIDN, 0, stream>>>(tB, rowptr, colx, tC);
  k_mm<0, 1><<<NN / 8, HIDN, 0, stream>>>(tC, w31, b31, scale, shift, tA);
  k_bn<<<HIDN, 256, 0, stream>>>(tA, g3, be3, scale, shift);
  k_lin3<<<NN, HIDN, 0, stream>>>(tA, scale, shift, w32, b32, p);

  k_q0<<<8, 256, 0, stream>>>(p, rowptr, colx, q0);
  k_loss<<<1, 256, 0, stream>>>(ent, p, q0, seggam, scal);
  k_sort<<<1, 1024, 0, stream>>>(p, order);
  k_greedy<<<1, 64, 0, stream>>>(rowptr, colx, triptr, tri, order, p, ent, q0, scal, selb);

  k_reach<<<NN / 2, 64, 0, stream>>>(rowbits, rowptr, colx, row2);
  k_reach<<<NN / 2, 64, 0, stream>>>(row2, rowptr, colx, row3);
  k_out<<<NN * NN / 256, 256, 0, stream>>>(row2, row3, selb, x, batch, scal,
                                           o_x, o_adj, o_sel, o_bat, o_loss);

  (void)in_sizes; (void)n_in; (void)out_size; (void)ws_size;
}

// Round 4
// 1178.782 us; speedup vs baseline: 1.9561x; 1.2783x over previous
//
#include <hip/hip_runtime.h>
#include <math.h>

#define NN 2048
#define DIMF 256
#define HIDN 128
#define NG 8
#define NEDGES 32768
#define W32 32
#define TRI_CAP 131072
#define TRI_LDS 4864

typedef unsigned long long u64;
typedef unsigned char u8;
typedef unsigned short u16;

// ---------------- build adjacency ----------------
__global__ void k_init(u64* __restrict__ rowbits, int* __restrict__ segstart) {
  int i = blockIdx.x * blockDim.x + threadIdx.x;
  for (int k = i; k < NN * W32; k += gridDim.x * blockDim.x) rowbits[k] = 0ull;
  if (i <= NG) segstart[i] = NN;
}

__global__ void k_edges(const int* __restrict__ ei, u64* __restrict__ rowbits) {
  int e = blockIdx.x * blockDim.x + threadIdx.x;
  if (e >= NEDGES) return;
  int u = ei[e], v = ei[NEDGES + e];
  atomicOr(&rowbits[((size_t)u << 5) + (v >> 6)], 1ull << (v & 63));
}

// deg + segment bounds (fused)
__global__ void k_deg(const u64* __restrict__ rowbits, int* __restrict__ deg,
                      const int* __restrict__ batch, int* __restrict__ segstart) {
  int i = blockIdx.x * blockDim.x + threadIdx.x;
  if (i >= NN) return;
  int c = 0;
  for (int w = 0; w < W32; ++w) c += __popcll(rowbits[(i << 5) + w]);
  deg[i] = c;
  if (i == 0 || batch[i] != batch[i - 1]) segstart[batch[i]] = i;
}

// exclusive scan of 2048 ints -> out[0..2048]
__global__ void k_scan2048(const int* __restrict__ in, int* __restrict__ out) {
  __shared__ int part[256];
  int t = threadIdx.x;
  int v[8]; int s = 0;
  for (int k = 0; k < 8; ++k) { v[k] = in[t * 8 + k]; s += v[k]; }
  part[t] = s;
  __syncthreads();
  for (int off = 1; off < 256; off <<= 1) {
    int y = (t >= off) ? part[t - off] : 0;
    __syncthreads();
    part[t] += y;
    __syncthreads();
  }
  int run = part[t] - s;
  for (int k = 0; k < 8; ++k) { out[t * 8 + k] = run; run += v[k]; }
  if (t == 255) out[NN] = part[255];
}

// extract CSR + count triangle pairs (fused)
__global__ void k_extract(const u64* __restrict__ rowbits, const int* __restrict__ rp,
                          int* __restrict__ col, int* __restrict__ cnt) {
  int i = blockIdx.x * blockDim.x + threadIdx.x;
  if (i >= NN) return;
  const u64* ri = rowbits + ((size_t)i << 5);
  int o = rp[i];
  for (int w = 0; w < W32; ++w) {
    u64 b = ri[w];
    while (b) { col[o++] = (w << 6) + __builtin_ctzll(b); b &= b - 1; }
  }
  int c = 0;
  for (int e = rp[i]; e < o; ++e) {
    const u64* ra = rowbits + ((size_t)col[e] << 5);
    for (int w = 0; w < W32; ++w) c += __popcll(ra[w] & ri[w]);
  }
  cnt[i] = c;
}

__global__ void k_trifill(const u64* __restrict__ rowbits, const int* __restrict__ rp,
                          const int* __restrict__ col, const int* __restrict__ tp,
                          int2* __restrict__ tri) {
  int i = blockIdx.x * blockDim.x + threadIdx.x;
  if (i >= NN) return;
  const u64* ri = rowbits + ((size_t)i << 5);
  int o = tp[i];
  for (int e = rp[i]; e < rp[i + 1]; ++e) {
    int a = col[e];
    const u64* ra = rowbits + ((size_t)a << 5);
    for (int w = 0; w < W32; ++w) {
      u64 b = ra[w] & ri[w];
      while (b) {
        int j = (w << 6) + __builtin_ctzll(b);
        if (o < TRI_CAP) tri[o] = make_int2(a, j);
        ++o;
        b &= b - 1;
      }
    }
  }
}

// ---------------- entropy term ----------------
__global__ void k_V(const float* __restrict__ x, const int* __restrict__ rp,
                    const int* __restrict__ col, float* __restrict__ V) {
  int i = blockIdx.x; int t = threadIdx.x; // 256 threads = dims
  float xi = x[i * DIMF + t];
  float s1 = 0.f, s2 = 0.f;
  int r0 = rp[i], r1 = rp[i + 1];
  for (int e = r0; e < r1; ++e) {
    float xj = x[col[e] * DIMF + t];
    s1 += xj; s2 += xj * xj;
  }
  float dg = (float)(r1 - r0);
  float val = dg * xi * xi - 2.f * xi * s1 + s2;
  __shared__ double red[DIMF];
  red[t] = (double)val * (double)val;
  __syncthreads();
  for (int off = DIMF / 2; off > 0; off >>= 1) { if (t < off) red[t] += red[t + off]; __syncthreads(); }
  if (t == 0) V[i] = (float)sqrt(red[0]);
}

__global__ void k_soft(const float* __restrict__ V, const int* __restrict__ segstart,
                       float* __restrict__ ent, double* __restrict__ seggamma) {
  int g = blockIdx.x; int t = threadIdx.x;
  int s = segstart[g];
  int e = NN;
  for (int gg = g + 1; gg <= NG; ++gg) { int v = segstart[gg]; if (v < e) e = v; }
  if (s >= e) { if (t == 0) seggamma[g] = 0.0; return; }
  __shared__ float fm[256];
  __shared__ double dd[256];
  float m = -3.0e38f;
  for (int i = s + t; i < e; i += 256) m = fmaxf(m, V[i]);
  fm[t] = m; __syncthreads();
  for (int off = 128; off > 0; off >>= 1) { if (t < off) fm[t] = fmaxf(fm[t], fm[t + off]); __syncthreads(); }
  float mx = fm[0];
  __syncthreads();
  double sum = 0.0;
  for (int i = s + t; i < e; i += 256) sum += exp((double)V[i] - (double)mx);
  dd[t] = sum; __syncthreads();
  for (int off = 128; off > 0; off >>= 1) { if (t < off) dd[t] += dd[t + off]; __syncthreads(); }
  double tot = dd[0];
  __syncthreads();
  double gs = 0.0;
  for (int i = s + t; i < e; i += 256) {
    double P = exp((double)V[i] - (double)mx) / tot;
    float ev = (P > 0.0) ? (float)(-P * log(P)) : 0.f;
    ent[i] = ev;
    gs += (double)ev;
  }
  dd[t] = gs; __syncthreads();
  for (int off = 128; off > 0; off >>= 1) { if (t < off) dd[t] += dd[t + off]; __syncthreads(); }
  if (t == 0) seggamma[g] = dd[0];
}

// ---------------- GIN MLPs ----------------
__global__ void k_agg1(const float* __restrict__ ent, const int* __restrict__ rp,
                       const int* __restrict__ col, float* __restrict__ agg) {
  int i = blockIdx.x * blockDim.x + threadIdx.x;
  if (i >= NN) return;
  float a = ent[i];
  for (int e = rp[i]; e < rp[i + 1]; ++e) a += ent[col[e]];
  agg[i] = a;
}

__global__ void k_lin1(const float* __restrict__ agg, const float* __restrict__ w,
                       const float* __restrict__ b, float* __restrict__ t) {
  int idx = blockIdx.x * blockDim.x + threadIdx.x;
  if (idx >= NN * HIDN) return;
  int i = idx >> 7, k = idx & 127;
  float v = agg[i] * w[k] + b[k];
  t[idx] = v > 0.f ? v : 0.f;
}

__global__ void k_bn(const float* __restrict__ t, const float* __restrict__ g,
                     const float* __restrict__ be, float* __restrict__ scale,
                     float* __restrict__ shift) {
  int k = blockIdx.x; int tid = threadIdx.x; // 256 threads per column
  __shared__ double red[256];
  double s = 0.0;
  for (int i = tid; i < NN; i += 256) s += (double)t[i * HIDN + k];
  red[tid] = s; __syncthreads();
  for (int off = 128; off > 0; off >>= 1) { if (tid < off) red[tid] += red[tid + off]; __syncthreads(); }
  double mu = red[0] / NN;
  __syncthreads();
  double v = 0.0;
  for (int i = tid; i < NN; i += 256) { double dv = (double)t[i * HIDN + k] - mu; v += dv * dv; }
  red[tid] = v; __syncthreads();
  for (int off = 128; off > 0; off >>= 1) { if (tid < off) red[tid] += red[tid + off]; __syncthreads(); }
  if (tid == 0) {
    float var = (float)(red[0] / NN);
    float sc = g[k] / sqrtf(var + 1e-5f);
    scale[k] = sc;
    shift[k] = be[k] - (float)mu * sc;
  }
}

template<int PRE, int RELU>
__global__ void k_mm(const float* __restrict__ in, const float* __restrict__ Wm,
                     const float* __restrict__ bias, const float* __restrict__ scale,
                     const float* __restrict__ shift, float* __restrict__ out) {
  __shared__ float ti[8][HIDN];
  int r0 = blockIdx.x * 8; int t = threadIdx.x; // 128 threads
  for (int r = 0; r < 8; ++r) {
    float v = in[(r0 + r) * HIDN + t];
    if (PRE) v = v * scale[t] + shift[t];
    ti[r][t] = v;
  }
  __syncthreads();
  float acc[8];
  #pragma unroll
  for (int r = 0; r < 8; ++r) acc[r] = 0.f;
  for (int k = 0; k < HIDN; ++k) {
    float w = Wm[k * HIDN + t];
    #pragma unroll
    for (int r = 0; r < 8; ++r) acc[r] += ti[r][k] * w;
  }
  for (int r = 0; r < 8; ++r) {
    float v = acc[r] + bias[t];
    if (RELU) v = fmaxf(v, 0.f);
    out[(r0 + r) * HIDN + t] = v;
  }
}

__global__ void k_agg128(const float* __restrict__ h, const int* __restrict__ rp,
                         const int* __restrict__ col, float* __restrict__ agg) {
  int i = blockIdx.x; int t = threadIdx.x; // 128 threads
  float a = h[i * HIDN + t];
  for (int e = rp[i]; e < rp[i + 1]; ++e) a += h[col[e] * HIDN + t];
  agg[i * HIDN + t] = a;
}

__global__ void k_lin3(const float* __restrict__ tn, const float* __restrict__ scale,
                       const float* __restrict__ shift, const float* __restrict__ w32,
                       const float* __restrict__ b32, float* __restrict__ p) {
  int i = blockIdx.x; int t = threadIdx.x; // 128
  float v = (tn[i * HIDN + t] * scale[t] + shift[t]) * w32[t];
  __shared__ float red[HIDN];
  red[t] = v; __syncthreads();
  for (int off = 64; off > 0; off >>= 1) { if (t < off) red[t] += red[t + off]; __syncthreads(); }
  if (t == 0) {
    float h3 = red[0] + b32[0];
    p[i] = 1.f / (1.f + expf(-h3));
  }
}

// ---------------- loss ----------------
__global__ void k_q0(const float* __restrict__ p, const int* __restrict__ rp,
                     const int* __restrict__ col, float* __restrict__ q0) {
  int i = blockIdx.x * blockDim.x + threadIdx.x;
  if (i >= NN) return;
  float s = 0.f;
  for (int e = rp[i]; e < rp[i + 1]; ++e) s += p[col[e]];
  q0[i] = s;
}

__global__ void k_loss(const float* __restrict__ ent, const float* __restrict__ p,
                       const float* __restrict__ q0, const double* __restrict__ seggamma,
                       double* __restrict__ scal) {
  __shared__ double ra[256], rb[256];
  int t = threadIdx.x;
  double a = 0.0, b = 0.0;
  for (int i = t; i < NN; i += 256) { a += (double)ent[i] * (double)p[i]; b += (double)p[i] * (double)q0[i]; }
  ra[t] = a; rb[t] = b; __syncthreads();
  for (int off = 128; off > 0; off >>= 1) {
    if (t < off) { ra[t] += ra[t + off]; rb[t] += rb[t + off]; }
    __syncthreads();
  }
  if (t == 0) {
    double gamma = 0.0;
    for (int g = 0; g < NG; ++g) gamma += seggamma[g];
    scal[0] = gamma; scal[1] = ra[0]; scal[2] = rb[0];
    scal[3] = gamma - ra[0] + rb[0];
  }
}

// ---------------- sort (descending p, stable) ----------------
__global__ void k_sort(const float* __restrict__ p, int* __restrict__ order) {
  __shared__ u64 s[NN];
  int t = threadIdx.x; // 1024
  for (int k = t; k < NN; k += 1024) {
    unsigned b = __float_as_uint(p[k]);
    unsigned ss = (b & 0x80000000u) ? ~b : (b | 0x80000000u);
    s[k] = ((u64)(~ss) << 32) | (unsigned)k;
  }
  __syncthreads();
  for (int k = 2; k <= NN; k <<= 1) {
    for (int j = k >> 1; j > 0; j >>= 1) {
      for (int i = t; i < NN; i += 1024) {
        int ixj = i ^ j;
        if (ixj > i) {
          bool up = ((i & k) == 0);
          u64 a = s[i], b = s[ixj];
          if ((a > b) == up) { s[i] = b; s[ixj] = a; }
        }
      }
      __syncthreads();
    }
  }
  order[t] = (int)(s[t] & 0xFFFFFFFFull);
  order[t + 1024] = (int)(s[t + 1024] & 0xFFFFFFFFull);
}

// ---------------- greedy: speculative batch evaluation (16 waves) ----------------
// Key fact: a rejected step changes NO state. Only accepts (~120) are sequential
// dependencies. Evaluate 16 order-positions concurrently (one wave each) against
// batch-start state; commit the FIRST accept in batch order; restart after it.
// Bit-identical to the sequential scan.
struct NodeF { float d, q, ent, pad; };

#define DPP4(ctrl)                                                                        \
  a += __int_as_float(__builtin_amdgcn_update_dpp(0, __float_as_int(a), ctrl, 0xf, 0xf, true)); \
  b += __int_as_float(__builtin_amdgcn_update_dpp(0, __float_as_int(b), ctrl, 0xf, 0xf, true)); \
  c += __int_as_float(__builtin_amdgcn_update_dpp(0, __float_as_int(c), ctrl, 0xf, 0xf, true)); \
  d += __int_as_float(__builtin_amdgcn_update_dpp(0, __float_as_int(d), ctrl, 0xf, 0xf, true));

__device__ __forceinline__ void red4(float& a, float& b, float& c, float& d) {
  DPP4(0x111)  // row_shr:1
  DPP4(0x112)  // row_shr:2
  DPP4(0x114)  // row_shr:4
  DPP4(0x118)  // row_shr:8
  DPP4(0x142)  // row_bcast:15
  DPP4(0x143)  // row_bcast:31
  a = __int_as_float(__builtin_amdgcn_readlane(__float_as_int(a), 63));
  b = __int_as_float(__builtin_amdgcn_readlane(__float_as_int(b), 63));
  c = __int_as_float(__builtin_amdgcn_readlane(__float_as_int(c), 63));
  d = __int_as_float(__builtin_amdgcn_readlane(__float_as_int(d), 63));
}

__global__ void __launch_bounds__(1024, 1) k_greedy(
    const int* __restrict__ rp, const int* __restrict__ col,
    const int* __restrict__ tp, const int2* __restrict__ tri,
    const int* __restrict__ order, const float* __restrict__ p,
    const float* __restrict__ ent, const float* __restrict__ q0,
    const double* __restrict__ scal, u8* __restrict__ selb_g) {
  __shared__ NodeF nd[NN];            // 32 KB
  __shared__ u16 colL[NEDGES];        // 64 KB
  __shared__ u16 ordl[NN];            // 4 KB
  __shared__ unsigned rtL[NN + 2];    // 8 KB: rp | tp<<16 packed
  __shared__ ushort2 triL[TRI_LDS];   // 19 KB
  __shared__ unsigned decidedL[64], selL[64];
  __shared__ int accf[2][16];
  __shared__ float svS1[2][16], svS2[2][16], svD0[2][16];
  __shared__ double svCr[2][16];
  __shared__ double edL, dAdL;
  int t = threadIdx.x;
  int w = t >> 6, lane = t & 63;

  for (int i = t; i < NN; i += 1024) {
    NodeF v; v.d = p[i]; v.q = q0[i]; v.ent = ent[i]; v.pad = 0.f;
    nd[i] = v;
    ordl[i] = (u16)order[i];
    int tv = tp[i]; if (tv > 65535) tv = 65535;
    rtL[i] = (unsigned)rp[i] | ((unsigned)tv << 16);
  }
  for (int i = t; i < NEDGES; i += 1024) colL[i] = (u16)col[i];
  for (int i = t; i < TRI_LDS; i += 1024) {
    int2 ab = tri[i];
    triL[i] = make_ushort2((u16)(ab.x & 2047), (u16)(ab.y & 2047));
  }
  if (t < 64) { decidedL[t] = 0u; selL[t] = 0u; }
  if (t == 0) {
    int tv = tp[NN]; if (tv > 65535) tv = 65535;
    rtL[NN] = (unsigned)rp[NN] | ((unsigned)tv << 16);
    edL = scal[1]; dAdL = scal[2];
  }
  double gamma = scal[0], loss = scal[3];
  __syncthreads();
  // pre-decide isolated nodes (selected; d never changes for them)
  for (int i = t; i < NN; i += 1024) {
    if (((rtL[i + 1] & 0xffffu) - (rtL[i] & 0xffffu)) == 0u) {
      atomicOr(&decidedL[i >> 5], 1u << (i & 31));
      atomicOr(&selL[i >> 5], 1u << (i & 31));
    }
  }
  __syncthreads();

  int pos = 0, rc = 0;
  while (pos < NN) {
    int b = rc & 1; ++rc;
    int accept = 0;
    float S1f = 0.f, S2f = 0.f, d0 = 0.f;
    double crossD = 0.0;
    int step = pos + w;
    if (step < NN) {
      int idx = ordl[step];
      if (!((decidedL[idx >> 5] >> (idx & 31)) & 1u)) {
        unsigned w0 = rtL[idx], w1 = rtL[idx + 1];
        int r0 = w0 & 0xffff, r1 = w1 & 0xffff;
        int t0 = w0 >> 16, t1 = w1 >> 16;
        NodeF vi = nd[idx];
        float s1 = 0.f, s2 = 0.f, sn = 0.f, st = 0.f;
        for (int e = r0 + lane; e < r1; e += 64) {
          int j = colL[e];
          NodeF v = nd[j];
          s1 -= v.ent * v.d; s2 -= v.q * v.d; sn -= v.d;
        }
        if (t1 <= TRI_LDS) {
          for (int e = t0 + lane; e < t1; e += 64) {
            ushort2 ab = triL[e];
            st += nd[ab.x].d * nd[ab.y].d;
          }
        } else {  // rare overflow: true offsets + pairs from global
          int g0 = tp[idx], g1 = tp[idx + 1];
          if (g0 > TRI_CAP) g0 = TRI_CAP;
          if (g1 > TRI_CAP) g1 = TRI_CAP;
          for (int e = g0 + lane; e < g1; e += 64) {
            int2 ab = tri[e];
            st += nd[ab.x].d * nd[ab.y].d;
          }
        }
        red4(s1, s2, sn, st);
        d0 = 1.f - vi.d;
        S1f = s1 + vi.ent * d0;
        S2f = s2 + vi.q * d0;
        crossD = 2.0 * (double)d0 * (double)sn + (double)st;
        double li = gamma - (edL + (double)S1f) + (dAdL + 2.0 * (double)S2f + crossD);
        accept = (li <= loss) ? 1 : 0;
      }
    }
    if (lane == 0) {
      accf[b][w] = accept;
      svS1[b][w] = S1f; svS2[b][w] = S2f; svD0[b][w] = d0; svCr[b][w] = crossD;
    }
    __syncthreads();
    unsigned mask = 0;
    #pragma unroll
    for (int i2 = 0; i2 < 16; ++i2) mask |= (accf[b][i2] ? 1u : 0u) << i2;
    if (mask == 0u) { pos += 16; continue; }
    int k = __builtin_ctz(mask);
    int idx = ordl[pos + k];
    float aS1 = svS1[b][k], aS2 = svS2[b][k], ad0 = svD0[b][k];
    double aCr = svCr[b][k];
    unsigned hw0 = rtL[idx], hw1 = rtL[idx + 1];
    int r0 = hw0 & 0xffff, r1 = hw1 & 0xffff;
    // phase 1: q scatter with OLD d (wave per neighbor; lanes over its adj list)
    for (int e = r0 + w; e < r1; e += 16) {
      int a = colL[e];
      float da = -nd[a].d;
      if (da != 0.f) {
        unsigned aw0 = rtL[a], aw1 = rtL[a + 1];
        int b0 = aw0 & 0xffff, b1 = aw1 & 0xffff;
        for (int eb = b0 + lane; eb < b1; eb += 64)
          atomicAdd(&nd[colL[eb]].q, da);
      }
    }
    for (int e = r0 + t; e < r1; e += 1024)
      atomicAdd(&nd[colL[e]].q, ad0);
    __syncthreads();
    // phase 2: d updates, decided/sel bits, running scalars
    if (t == 0) {
      nd[idx].d = 1.f;
      atomicOr(&decidedL[idx >> 5], 1u << (idx & 31));
      atomicOr(&selL[idx >> 5], 1u << (idx & 31));
      edL += (double)aS1;
      dAdL += 2.0 * (double)aS2 + aCr;
    }
    for (int e = r0 + t; e < r1; e += 1024) {
      int j = colL[e];
      nd[j].d = 0.f;
      atomicOr(&decidedL[j >> 5], 1u << (j & 31));
    }
    __syncthreads();
    pos += k + 1;
  }
  for (int i = t; i < NN; i += 1024)
    selb_g[i] = (u8)((selL[i >> 5] >> (i & 31)) & 1u);
}

// ---------------- boolean A^2 / A^3 ----------------
__global__ void k_reach(const u64* __restrict__ src, const int* __restrict__ rp,
                        const int* __restrict__ col, u64* __restrict__ dst) {
  int node = blockIdx.x * 2 + (threadIdx.x >> 5);
  int w = threadIdx.x & 31;
  u64 acc = 0;
  for (int e = rp[node]; e < rp[node + 1]; ++e) acc |= src[((size_t)col[e] << 5) + w];
  dst[((size_t)node << 5) + w] = acc;
}

// ---------------- outputs (fused) ----------------
__global__ void k_out(const u64* __restrict__ row2, const u64* __restrict__ row3,
                      const u8* __restrict__ selb, const float* __restrict__ x,
                      const int* __restrict__ batch, const double* __restrict__ scal,
                      float* __restrict__ o_x, float* __restrict__ o_adj,
                      float* __restrict__ o_sel, float* __restrict__ o_bat,
                      float* __restrict__ o_loss) {
  int idx = blockIdx.x * blockDim.x + threadIdx.x; // NN*NN
  {
    int i = idx >> 11, j = idx & 2047;
    int wo = (i << 5) + (j >> 6);
    u64 b = (row2[wo] | row3[wo]) >> (j & 63);
    o_adj[idx] = ((b & 1ull) && i != j && selb[i] && selb[j]) ? 1.f : 0.f;
  }
  if (idx < NN * DIMF) {
    int i = idx >> 8;
    o_x[idx] = selb[i] ? x[idx] : 0.f;
  }
  if (idx < NN) {
    o_sel[idx] = selb[idx] ? 1.f : 0.f;
    o_bat[idx] = selb[idx] ? (float)batch[idx] : -1.f;
  }
  if (idx == 0) o_loss[0] = (float)scal[3];
}

extern "C" void kernel_launch(void* const* d_in, const int* in_sizes, int n_in,
                              void* d_out, int out_size, void* d_ws, size_t ws_size,
                              hipStream_t stream) {
  const float* x    = (const float*)d_in[0];
  const int*   ei   = (const int*)d_in[1];
  const int*   batch= (const int*)d_in[2];
  const float* w11  = (const float*)d_in[3];
  const float* b11  = (const float*)d_in[4];
  const float* g1   = (const float*)d_in[5];
  const float* be1  = (const float*)d_in[6];
  const float* w12  = (const float*)d_in[7];
  const float* b12  = (const float*)d_in[8];
  const float* w21  = (const float*)d_in[9];
  const float* b21  = (const float*)d_in[10];
  const float* g2   = (const float*)d_in[11];
  const float* be2  = (const float*)d_in[12];
  const float* w22  = (const float*)d_in[13];
  const float* b22  = (const float*)d_in[14];
  const float* w31  = (const float*)d_in[15];
  const float* b31  = (const float*)d_in[16];
  const float* g3   = (const float*)d_in[17];
  const float* be3  = (const float*)d_in[18];
  const float* w32  = (const float*)d_in[19];
  const float* b32  = (const float*)d_in[20];

  char* wsb = (char*)d_ws;
  size_t cur = 0;
  auto alloc = [&](size_t bytes) -> void* {
    void* pp = wsb + cur;
    cur += (bytes + 255) & ~(size_t)255;
    return pp;
  };
  u64*    rowbits = (u64*)alloc((size_t)NN * W32 * 8);
  u64*    row2    = (u64*)alloc((size_t)NN * W32 * 8);
  u64*    row3    = (u64*)alloc((size_t)NN * W32 * 8);
  double* seggam  = (double*)alloc(NG * 8);
  double* scal    = (double*)alloc(4 * 8);
  int*    deg     = (int*)alloc(NN * 4);
  int*    rowptr  = (int*)alloc((NN + 1) * 4);
  int*    colx    = (int*)alloc(65536 * 4);
  int*    tricnt  = (int*)alloc(NN * 4);
  int*    triptr  = (int*)alloc((NN + 1) * 4);
  int2*   tri     = (int2*)alloc((size_t)TRI_CAP * 8);
  int*    segst   = (int*)alloc((NG + 1) * 4);
  int*    order   = (int*)alloc(NN * 4);
  float*  ent     = (float*)alloc(NN * 4);
  float*  V       = (float*)alloc(NN * 4);
  float*  p       = (float*)alloc(NN * 4);
  float*  q0      = (float*)alloc(NN * 4);
  float*  agg1    = (float*)alloc(NN * 4);
  float*  scale   = (float*)alloc(HIDN * 4);
  float*  shift   = (float*)alloc(HIDN * 4);
  float*  tA      = (float*)alloc((size_t)NN * HIDN * 4);
  float*  tB      = (float*)alloc((size_t)NN * HIDN * 4);
  float*  tC      = (float*)alloc((size_t)NN * HIDN * 4);
  u8*     selb    = (u8*)alloc(NN);

  float* out    = (float*)d_out;
  float* o_x    = out;                       // 524288
  float* o_adj  = out + 524288;              // 4194304
  float* o_sel  = out + 4718592;             // 2048
  float* o_bat  = out + 4720640;             // 2048
  float* o_loss = out + 4722688;             // 1

  k_init<<<64, 256, 0, stream>>>(rowbits, segst);
  k_edges<<<128, 256, 0, stream>>>(ei, rowbits);
  k_deg<<<8, 256, 0, stream>>>(rowbits, deg, batch, segst);
  k_scan2048<<<1, 256, 0, stream>>>(deg, rowptr);
  k_extract<<<8, 256, 0, stream>>>(rowbits, rowptr, colx, tricnt);
  k_scan2048<<<1, 256, 0, stream>>>(tricnt, triptr);
  k_trifill<<<8, 256, 0, stream>>>(rowbits, rowptr, colx, triptr, tri);
  k_V<<<NN, 256, 0, stream>>>(x, rowptr, colx, V);
  k_soft<<<NG, 256, 0, stream>>>(V, segst, ent, seggam);

  // layer 1
  k_agg1<<<8, 256, 0, stream>>>(ent, rowptr, colx, agg1);
  k_lin1<<<1024, 256, 0, stream>>>(agg1, w11, b11, tA);
  k_bn<<<HIDN, 256, 0, stream>>>(tA, g1, be1, scale, shift);
  k_mm<1, 0><<<NN / 8, HIDN, 0, stream>>>(tA, w12, b12, scale, shift, tB);
  // layer 2
  k_agg128<<<NN, HIDN, 0, stream>>>(tB, rowptr, colx, tC);
  k_mm<0, 1><<<NN / 8, HIDN, 0, stream>>>(tC, w21, b21, scale, shift, tA);
  k_bn<<<HIDN, 256, 0, stream>>>(tA, g2, be2, scale, shift);
  k_mm<1, 0><<<NN / 8, HIDN, 0, stream>>>(tA, w22, b22, scale, shift, tB);
  // layer 3
  k_agg128<<<NN, HIDN, 0, stream>>>(tB, rowptr, colx, tC);
  k_mm<0, 1><<<NN / 8, HIDN, 0, stream>>>(tC, w31, b31, scale, shift, tA);
  k_bn<<<HIDN, 256, 0, stream>>>(tA, g3, be3, scale, shift);
  k_lin3<<<NN, HIDN, 0, stream>>>(tA, scale, shift, w32, b32, p);

  k_q0<<<8, 256, 0, stream>>>(p, rowptr, colx, q0);
  k_loss<<<1, 256, 0, stream>>>(ent, p, q0, seggam, scal);
  k_sort<<<1, 1024, 0, stream>>>(p, order);
  k_greedy<<<1, 1024, 0, stream>>>(rowptr, colx, triptr, tri, order, p, ent, q0, scal, selb);

  k_reach<<<NN / 2, 64, 0, stream>>>(rowbits, rowptr, colx, row2);
  k_reach<<<NN / 2, 64, 0, stream>>>(row2, rowptr, colx, row3);
  k_out<<<NN * NN / 256, 256, 0, stream>>>(row2, row3, selb, x, batch, scal,
                                           o_x, o_adj, o_sel, o_bat, o_loss);

  (void)in_sizes; (void)n_in; (void)out_size; (void)ws_size;
}

// Round 5
// 1131.903 us; speedup vs baseline: 2.0371x; 1.0414x over previous
//
#include <hip/hip_runtime.h>
#include <math.h>

#define NN 2048
#define DIMF 256
#define HIDN 128
#define NG 8
#define NEDGES 32768
#define W32 32
#define TRI_CAP 131072
#define TRI_LDS 4864

typedef unsigned long long u64;
typedef unsigned char u8;
typedef unsigned short u16;

// ---------------- build adjacency ----------------
__global__ void k_init(u64* __restrict__ rowbits, int* __restrict__ segstart) {
  int i = blockIdx.x * blockDim.x + threadIdx.x;
  for (int k = i; k < NN * W32; k += gridDim.x * blockDim.x) rowbits[k] = 0ull;
  if (i <= NG) segstart[i] = NN;
}

__global__ void k_edges(const int* __restrict__ ei, u64* __restrict__ rowbits) {
  int e = blockIdx.x * blockDim.x + threadIdx.x;
  if (e >= NEDGES) return;
  int u = ei[e], v = ei[NEDGES + e];
  atomicOr(&rowbits[((size_t)u << 5) + (v >> 6)], 1ull << (v & 63));
}

// deg + segment bounds (fused)
__global__ void k_deg(const u64* __restrict__ rowbits, int* __restrict__ deg,
                      const int* __restrict__ batch, int* __restrict__ segstart) {
  int i = blockIdx.x * blockDim.x + threadIdx.x;
  if (i >= NN) return;
  int c = 0;
  for (int w = 0; w < W32; ++w) c += __popcll(rowbits[(i << 5) + w]);
  deg[i] = c;
  if (i == 0 || batch[i] != batch[i - 1]) segstart[batch[i]] = i;
}

// exclusive scan of 2048 ints -> out[0..2048]
__global__ void k_scan2048(const int* __restrict__ in, int* __restrict__ out) {
  __shared__ int part[256];
  int t = threadIdx.x;
  int v[8]; int s = 0;
  for (int k = 0; k < 8; ++k) { v[k] = in[t * 8 + k]; s += v[k]; }
  part[t] = s;
  __syncthreads();
  for (int off = 1; off < 256; off <<= 1) {
    int y = (t >= off) ? part[t - off] : 0;
    __syncthreads();
    part[t] += y;
    __syncthreads();
  }
  int run = part[t] - s;
  for (int k = 0; k < 8; ++k) { out[t * 8 + k] = run; run += v[k]; }
  if (t == 255) out[NN] = part[255];
}

// extract CSR + count triangle pairs (fused)
__global__ void k_extract(const u64* __restrict__ rowbits, const int* __restrict__ rp,
                          int* __restrict__ col, int* __restrict__ cnt) {
  int i = blockIdx.x * blockDim.x + threadIdx.x;
  if (i >= NN) return;
  const u64* ri = rowbits + ((size_t)i << 5);
  int o = rp[i];
  for (int w = 0; w < W32; ++w) {
    u64 b = ri[w];
    while (b) { col[o++] = (w << 6) + __builtin_ctzll(b); b &= b - 1; }
  }
  int c = 0;
  for (int e = rp[i]; e < o; ++e) {
    const u64* ra = rowbits + ((size_t)col[e] << 5);
    for (int w = 0; w < W32; ++w) c += __popcll(ra[w] & ri[w]);
  }
  cnt[i] = c;
}

__global__ void k_trifill(const u64* __restrict__ rowbits, const int* __restrict__ rp,
                          const int* __restrict__ col, const int* __restrict__ tp,
                          int2* __restrict__ tri) {
  int i = blockIdx.x * blockDim.x + threadIdx.x;
  if (i >= NN) return;
  const u64* ri = rowbits + ((size_t)i << 5);
  int o = tp[i];
  for (int e = rp[i]; e < rp[i + 1]; ++e) {
    int a = col[e];
    const u64* ra = rowbits + ((size_t)a << 5);
    for (int w = 0; w < W32; ++w) {
      u64 b = ra[w] & ri[w];
      while (b) {
        int j = (w << 6) + __builtin_ctzll(b);
        if (o < TRI_CAP) tri[o] = make_int2(a, j);
        ++o;
        b &= b - 1;
      }
    }
  }
}

// ---------------- entropy term ----------------
__global__ void k_V(const float* __restrict__ x, const int* __restrict__ rp,
                    const int* __restrict__ col, float* __restrict__ V) {
  int i = blockIdx.x; int t = threadIdx.x; // 256 threads = dims
  float xi = x[i * DIMF + t];
  float s1 = 0.f, s2 = 0.f;
  int r0 = rp[i], r1 = rp[i + 1];
  for (int e = r0; e < r1; ++e) {
    float xj = x[col[e] * DIMF + t];
    s1 += xj; s2 += xj * xj;
  }
  float dg = (float)(r1 - r0);
  float val = dg * xi * xi - 2.f * xi * s1 + s2;
  __shared__ double red[DIMF];
  red[t] = (double)val * (double)val;
  __syncthreads();
  for (int off = DIMF / 2; off > 0; off >>= 1) { if (t < off) red[t] += red[t + off]; __syncthreads(); }
  if (t == 0) V[i] = (float)sqrt(red[0]);
}

__global__ void k_soft(const float* __restrict__ V, const int* __restrict__ segstart,
                       float* __restrict__ ent, double* __restrict__ seggamma) {
  int g = blockIdx.x; int t = threadIdx.x;
  int s = segstart[g];
  int e = NN;
  for (int gg = g + 1; gg <= NG; ++gg) { int v = segstart[gg]; if (v < e) e = v; }
  if (s >= e) { if (t == 0) seggamma[g] = 0.0; return; }
  __shared__ float fm[256];
  __shared__ double dd[256];
  float m = -3.0e38f;
  for (int i = s + t; i < e; i += 256) m = fmaxf(m, V[i]);
  fm[t] = m; __syncthreads();
  for (int off = 128; off > 0; off >>= 1) { if (t < off) fm[t] = fmaxf(fm[t], fm[t + off]); __syncthreads(); }
  float mx = fm[0];
  __syncthreads();
  double sum = 0.0;
  for (int i = s + t; i < e; i += 256) sum += exp((double)V[i] - (double)mx);
  dd[t] = sum; __syncthreads();
  for (int off = 128; off > 0; off >>= 1) { if (t < off) dd[t] += dd[t + off]; __syncthreads(); }
  double tot = dd[0];
  __syncthreads();
  double gs = 0.0;
  for (int i = s + t; i < e; i += 256) {
    double P = exp((double)V[i] - (double)mx) / tot;
    float ev = (P > 0.0) ? (float)(-P * log(P)) : 0.f;
    ent[i] = ev;
    gs += (double)ev;
  }
  dd[t] = gs; __syncthreads();
  for (int off = 128; off > 0; off >>= 1) { if (t < off) dd[t] += dd[t + off]; __syncthreads(); }
  if (t == 0) seggamma[g] = dd[0];
}

// ---------------- GIN MLPs ----------------
__global__ void k_agg1(const float* __restrict__ ent, const int* __restrict__ rp,
                       const int* __restrict__ col, float* __restrict__ agg) {
  int i = blockIdx.x * blockDim.x + threadIdx.x;
  if (i >= NN) return;
  float a = ent[i];
  for (int e = rp[i]; e < rp[i + 1]; ++e) a += ent[col[e]];
  agg[i] = a;
}

__global__ void k_lin1(const float* __restrict__ agg, const float* __restrict__ w,
                       const float* __restrict__ b, float* __restrict__ t) {
  int idx = blockIdx.x * blockDim.x + threadIdx.x;
  if (idx >= NN * HIDN) return;
  int i = idx >> 7, k = idx & 127;
  float v = agg[i] * w[k] + b[k];
  t[idx] = v > 0.f ? v : 0.f;
}

__global__ void k_bn(const float* __restrict__ t, const float* __restrict__ g,
                     const float* __restrict__ be, float* __restrict__ scale,
                     float* __restrict__ shift) {
  int k = blockIdx.x; int tid = threadIdx.x; // 256 threads per column
  __shared__ double red[256];
  double s = 0.0;
  for (int i = tid; i < NN; i += 256) s += (double)t[i * HIDN + k];
  red[tid] = s; __syncthreads();
  for (int off = 128; off > 0; off >>= 1) { if (tid < off) red[tid] += red[tid + off]; __syncthreads(); }
  double mu = red[0] / NN;
  __syncthreads();
  double v = 0.0;
  for (int i = tid; i < NN; i += 256) { double dv = (double)t[i * HIDN + k] - mu; v += dv * dv; }
  red[tid] = v; __syncthreads();
  for (int off = 128; off > 0; off >>= 1) { if (tid < off) red[tid] += red[tid + off]; __syncthreads(); }
  if (tid == 0) {
    float var = (float)(red[0] / NN);
    float sc = g[k] / sqrtf(var + 1e-5f);
    scale[k] = sc;
    shift[k] = be[k] - (float)mu * sc;
  }
}

template<int PRE, int RELU>
__global__ void k_mm(const float* __restrict__ in, const float* __restrict__ Wm,
                     const float* __restrict__ bias, const float* __restrict__ scale,
                     const float* __restrict__ shift, float* __restrict__ out) {
  __shared__ float ti[8][HIDN];
  int r0 = blockIdx.x * 8; int t = threadIdx.x; // 128 threads
  for (int r = 0; r < 8; ++r) {
    float v = in[(r0 + r) * HIDN + t];
    if (PRE) v = v * scale[t] + shift[t];
    ti[r][t] = v;
  }
  __syncthreads();
  float acc[8];
  #pragma unroll
  for (int r = 0; r < 8; ++r) acc[r] = 0.f;
  for (int k = 0; k < HIDN; ++k) {
    float w = Wm[k * HIDN + t];
    #pragma unroll
    for (int r = 0; r < 8; ++r) acc[r] += ti[r][k] * w;
  }
  for (int r = 0; r < 8; ++r) {
    float v = acc[r] + bias[t];
    if (RELU) v = fmaxf(v, 0.f);
    out[(r0 + r) * HIDN + t] = v;
  }
}

__global__ void k_agg128(const float* __restrict__ h, const int* __restrict__ rp,
                         const int* __restrict__ col, float* __restrict__ agg) {
  int i = blockIdx.x; int t = threadIdx.x; // 128 threads
  float a = h[i * HIDN + t];
  for (int e = rp[i]; e < rp[i + 1]; ++e) a += h[col[e] * HIDN + t];
  agg[i * HIDN + t] = a;
}

__global__ void k_lin3(const float* __restrict__ tn, const float* __restrict__ scale,
                       const float* __restrict__ shift, const float* __restrict__ w32,
                       const float* __restrict__ b32, float* __restrict__ p) {
  int i = blockIdx.x; int t = threadIdx.x; // 128
  float v = (tn[i * HIDN + t] * scale[t] + shift[t]) * w32[t];
  __shared__ float red[HIDN];
  red[t] = v; __syncthreads();
  for (int off = 64; off > 0; off >>= 1) { if (t < off) red[t] += red[t + off]; __syncthreads(); }
  if (t == 0) {
    float h3 = red[0] + b32[0];
    p[i] = 1.f / (1.f + expf(-h3));
  }
}

// ---------------- loss (q0 also computes E0 = sum ent_j * p_j over neighbors) --------
__global__ void k_q0(const float* __restrict__ p, const float* __restrict__ ent,
                     const int* __restrict__ rp, const int* __restrict__ col,
                     float* __restrict__ q0, float* __restrict__ e0) {
  int i = blockIdx.x * blockDim.x + threadIdx.x;
  if (i >= NN) return;
  float s = 0.f, es = 0.f;
  for (int e = rp[i]; e < rp[i + 1]; ++e) {
    int j = col[e];
    float pj = p[j];
    s += pj; es += ent[j] * pj;
  }
  q0[i] = s; e0[i] = es;
}

__global__ void k_loss(const float* __restrict__ ent, const float* __restrict__ p,
                       const float* __restrict__ q0, const double* __restrict__ seggamma,
                       double* __restrict__ scal) {
  __shared__ double ra[256], rb[256];
  int t = threadIdx.x;
  double a = 0.0, b = 0.0;
  for (int i = t; i < NN; i += 256) { a += (double)ent[i] * (double)p[i]; b += (double)p[i] * (double)q0[i]; }
  ra[t] = a; rb[t] = b; __syncthreads();
  for (int off = 128; off > 0; off >>= 1) {
    if (t < off) { ra[t] += ra[t + off]; rb[t] += rb[t + off]; }
    __syncthreads();
  }
  if (t == 0) {
    double gamma = 0.0;
    for (int g = 0; g < NG; ++g) gamma += seggamma[g];
    scal[0] = gamma; scal[1] = ra[0]; scal[2] = rb[0];
    scal[3] = gamma - ra[0] + rb[0];
  }
}

// ---------------- sort (descending p, stable) ----------------
__global__ void k_sort(const float* __restrict__ p, int* __restrict__ order) {
  __shared__ u64 s[NN];
  int t = threadIdx.x; // 1024
  for (int k = t; k < NN; k += 1024) {
    unsigned b = __float_as_uint(p[k]);
    unsigned ss = (b & 0x80000000u) ? ~b : (b | 0x80000000u);
    s[k] = ((u64)(~ss) << 32) | (unsigned)k;
  }
  __syncthreads();
  for (int k = 2; k <= NN; k <<= 1) {
    for (int j = k >> 1; j > 0; j >>= 1) {
      for (int i = t; i < NN; i += 1024) {
        int ixj = i ^ j;
        if (ixj > i) {
          bool up = ((i & k) == 0);
          u64 a = s[i], b = s[ixj];
          if ((a > b) == up) { s[i] = b; s[ixj] = a; }
        }
      }
      __syncthreads();
    }
  }
  order[t] = (int)(s[t] & 0xFFFFFFFFull);
  order[t + 1024] = (int)(s[t + 1024] & 0xFFFFFFFFull);
}

// ---------------- greedy: speculative batch (16 waves), LDS-traffic-minimized -------
// sn = -q[idx] (q maintained), s1 = -E[idx] + ent_i*d0 (E maintained by the same
// accept scatter as q). Eval reduces only {s2, st}. Mask is one LDS u32.
#define DPP2(ctrl)                                                                        \
  a += __int_as_float(__builtin_amdgcn_update_dpp(0, __float_as_int(a), ctrl, 0xf, 0xf, true)); \
  b += __int_as_float(__builtin_amdgcn_update_dpp(0, __float_as_int(b), ctrl, 0xf, 0xf, true));

__device__ __forceinline__ void red2(float& a, float& b) {
  DPP2(0x111)  // row_shr:1
  DPP2(0x112)  // row_shr:2
  DPP2(0x114)  // row_shr:4
  DPP2(0x118)  // row_shr:8
  DPP2(0x142)  // row_bcast:15
  DPP2(0x143)  // row_bcast:31
  a = __int_as_float(__builtin_amdgcn_readlane(__float_as_int(a), 63));
  b = __int_as_float(__builtin_amdgcn_readlane(__float_as_int(b), 63));
}

__global__ void __launch_bounds__(1024, 1) k_greedy(
    const int* __restrict__ rp, const int* __restrict__ col,
    const int* __restrict__ tp, const int2* __restrict__ tri,
    const int* __restrict__ order, const float* __restrict__ p,
    const float* __restrict__ ent, const float* __restrict__ q0,
    const float* __restrict__ e0, const double* __restrict__ scal,
    u8* __restrict__ selb_g) {
  __shared__ float2 dq[NN];           // 16 KB {d, q}
  __shared__ float2 ee[NN];           // 16 KB {ent, E}
  __shared__ u16 colL[NEDGES];        // 64 KB
  __shared__ u16 ordl[NN];            // 4 KB
  __shared__ uint2 rtP[NN + 1];       // 16 KB {rp|tp<<16 at i, at i+1}
  __shared__ ushort2 triL[TRI_LDS];   // 19 KB
  __shared__ unsigned decidedL[64], selL[64];
  __shared__ unsigned maskL[2];
  __shared__ float4 svA[2][16];       // {S1, S2, d0, st}
  int t = threadIdx.x;
  int w = t >> 6, lane = t & 63;

  for (int i = t; i < NN; i += 1024) {
    dq[i] = make_float2(p[i], q0[i]);
    ee[i] = make_float2(ent[i], e0[i]);
    ordl[i] = (u16)order[i];
    int tv0 = tp[i]; if (tv0 > 65535) tv0 = 65535;
    int tv1 = tp[i + 1]; if (tv1 > 65535) tv1 = 65535;
    rtP[i] = make_uint2((unsigned)rp[i] | ((unsigned)tv0 << 16),
                        (unsigned)rp[i + 1] | ((unsigned)tv1 << 16));
  }
  for (int i = t; i < NEDGES; i += 1024) colL[i] = (u16)col[i];
  for (int i = t; i < TRI_LDS; i += 1024) {
    int2 ab = tri[i];
    triL[i] = make_ushort2((u16)(ab.x & 2047), (u16)(ab.y & 2047));
  }
  if (t < 64) { decidedL[t] = 0u; selL[t] = 0u; }
  if (t < 2) maskL[t] = 0u;
  double gamma = scal[0], loss = scal[3];
  double ed = scal[1], dAd = scal[2];  // replicated per-thread registers
  __syncthreads();
  // pre-decide isolated nodes (selected; never touched again)
  for (int i = t; i < NN; i += 1024) {
    if (((rtP[i].y & 0xffffu) - (rtP[i].x & 0xffffu)) == 0u) {
      atomicOr(&decidedL[i >> 5], 1u << (i & 31));
      atomicOr(&selL[i >> 5], 1u << (i & 31));
    }
  }
  __syncthreads();

  int pos = 0, rc = 0;
  while (pos < NN) {
    int b = rc & 1; ++rc;
    int step = pos + w;
    if (step < NN) {
      int idx = ordl[step];
      if (!((decidedL[idx >> 5] >> (idx & 31)) & 1u)) {
        uint2 rt = rtP[idx];
        int r0 = rt.x & 0xffff, r1 = rt.y & 0xffff;
        int t0 = rt.x >> 16, t1 = rt.y >> 16;
        float2 dqi = dq[idx];   // broadcast
        float2 eei = ee[idx];   // broadcast
        float s2 = 0.f, st = 0.f;
        for (int e = r0 + lane; e < r1; e += 64) {
          float2 v = dq[colL[e]];
          s2 -= v.y * v.x;
        }
        if (t1 <= TRI_LDS) {
          for (int e = t0 + lane; e < t1; e += 64) {
            ushort2 ab = triL[e];
            st += dq[ab.x].x * dq[ab.y].x;
          }
        } else {  // rare overflow: true offsets + pairs from global
          int g0 = tp[idx], g1 = tp[idx + 1];
          if (g0 > TRI_CAP) g0 = TRI_CAP;
          if (g1 > TRI_CAP) g1 = TRI_CAP;
          for (int e = g0 + lane; e < g1; e += 64) {
            int2 ab = tri[e];
            st += dq[ab.x].x * dq[ab.y].x;
          }
        }
        red2(s2, st);
        float d0 = 1.f - dqi.x;
        float S1 = -eei.y + eei.x * d0;
        float S2 = s2 + dqi.y * d0;
        float sn = -dqi.y;
        double cross = 2.0 * (double)d0 * (double)sn + (double)st;
        double li = gamma - (ed + (double)S1) + (dAd + 2.0 * (double)S2 + cross);
        if (li <= loss && lane == 0) {
          svA[b][w] = make_float4(S1, S2, d0, st);
          atomicOr(&maskL[b], 1u << w);
        }
      }
    }
    __syncthreads();
    unsigned mask = maskL[b];
    if (mask == 0u) { pos += 16; continue; }
    int k = __builtin_ctz(mask);
    int idx = ordl[pos + k];
    float4 A = svA[b][k];     // broadcast: {S1, S2, d0, st}
    float2 dqi = dq[idx];     // old q_idx (pre-scatter)
    uint2 rt = rtP[idx];
    int r0 = rt.x & 0xffff, r1 = rt.y & 0xffff;
    // all threads replicate scalar updates (identical f64 ops -> consistent)
    {
      double cross = 2.0 * (double)A.z * (double)(-dqi.y) + (double)A.w;
      ed += (double)A.x;
      dAd += 2.0 * (double)A.y + cross;
    }
    __syncthreads();  // all reads of dq/maskL complete before scatter
    if (t == 0) maskL[b] = 0u;
    // phase 1: q/E scatter with OLD d (wave per changed neighbor)
    for (int e = r0 + w; e < r1; e += 16) {
      int a = colL[e];
      float da = -dq[a].x;
      if (da != 0.f) {
        float ea = ee[a].x;
        uint2 art = rtP[a];
        int b0 = art.x & 0xffff, b1 = art.y & 0xffff;
        for (int eb = b0 + lane; eb < b1; eb += 64) {
          int bb = colL[eb];
          atomicAdd(&dq[bb].y, da);
          atomicAdd(&ee[bb].y, ea * da);
        }
      }
    }
    {
      float ei = ee[idx].x;
      for (int e = r0 + t; e < r1; e += 1024) {
        int bb = colL[e];
        atomicAdd(&dq[bb].y, A.z);
        atomicAdd(&ee[bb].y, ei * A.z);
      }
    }
    __syncthreads();
    // phase 2: d updates + decided/sel bits
    if (t == 0) {
      dq[idx].x = 1.f;
      atomicOr(&decidedL[idx >> 5], 1u << (idx & 31));
      atomicOr(&selL[idx >> 5], 1u << (idx & 31));
    }
    for (int e = r0 + t; e < r1; e += 1024) {
      int j = colL[e];
      dq[j].x = 0.f;
      atomicOr(&decidedL[j >> 5], 1u << (j & 31));
    }
    __syncthreads();
    pos += k + 1;
  }
  for (int i = t; i < NN; i += 1024)
    selb_g[i] = (u8)((selL[i >> 5] >> (i & 31)) & 1u);
}

// ---------------- boolean A^2 / A^3 ----------------
__global__ void k_reach(const u64* __restrict__ src, const int* __restrict__ rp,
                        const int* __restrict__ col, u64* __restrict__ dst) {
  int node = blockIdx.x * 2 + (threadIdx.x >> 5);
  int w = threadIdx.x & 31;
  u64 acc = 0;
  for (int e = rp[node]; e < rp[node + 1]; ++e) acc |= src[((size_t)col[e] << 5) + w];
  dst[((size_t)node << 5) + w] = acc;
}

// ---------------- outputs (fused) ----------------
__global__ void k_out(const u64* __restrict__ row2, const u64* __restrict__ row3,
                      const u8* __restrict__ selb, const float* __restrict__ x,
                      const int* __restrict__ batch, const double* __restrict__ scal,
                      float* __restrict__ o_x, float* __restrict__ o_adj,
                      float* __restrict__ o_sel, float* __restrict__ o_bat,
                      float* __restrict__ o_loss) {
  int idx = blockIdx.x * blockDim.x + threadIdx.x; // NN*NN
  {
    int i = idx >> 11, j = idx & 2047;
    int wo = (i << 5) + (j >> 6);
    u64 b = (row2[wo] | row3[wo]) >> (j & 63);
    o_adj[idx] = ((b & 1ull) && i != j && selb[i] && selb[j]) ? 1.f : 0.f;
  }
  if (idx < NN * DIMF) {
    int i = idx >> 8;
    o_x[idx] = selb[i] ? x[idx] : 0.f;
  }
  if (idx < NN) {
    o_sel[idx] = selb[idx] ? 1.f : 0.f;
    o_bat[idx] = selb[idx] ? (float)batch[idx] : -1.f;
  }
  if (idx == 0) o_loss[0] = (float)scal[3];
}

extern "C" void kernel_launch(void* const* d_in, const int* in_sizes, int n_in,
                              void* d_out, int out_size, void* d_ws, size_t ws_size,
                              hipStream_t stream) {
  const float* x    = (const float*)d_in[0];
  const int*   ei   = (const int*)d_in[1];
  const int*   batch= (const int*)d_in[2];
  const float* w11  = (const float*)d_in[3];
  const float* b11  = (const float*)d_in[4];
  const float* g1   = (const float*)d_in[5];
  const float* be1  = (const float*)d_in[6];
  const float* w12  = (const float*)d_in[7];
  const float* b12  = (const float*)d_in[8];
  const float* w21  = (const float*)d_in[9];
  const float* b21  = (const float*)d_in[10];
  const float* g2   = (const float*)d_in[11];
  const float* be2  = (const float*)d_in[12];
  const float* w22  = (const float*)d_in[13];
  const float* b22  = (const float*)d_in[14];
  const float* w31  = (const float*)d_in[15];
  const float* b31  = (const float*)d_in[16];
  const float* g3   = (const float*)d_in[17];
  const float* be3  = (const float*)d_in[18];
  const float* w32  = (const float*)d_in[19];
  const float* b32  = (const float*)d_in[20];

  char* wsb = (char*)d_ws;
  size_t cur = 0;
  auto alloc = [&](size_t bytes) -> void* {
    void* pp = wsb + cur;
    cur += (bytes + 255) & ~(size_t)255;
    return pp;
  };
  u64*    rowbits = (u64*)alloc((size_t)NN * W32 * 8);
  u64*    row2    = (u64*)alloc((size_t)NN * W32 * 8);
  u64*    row3    = (u64*)alloc((size_t)NN * W32 * 8);
  double* seggam  = (double*)alloc(NG * 8);
  double* scal    = (double*)alloc(4 * 8);
  int*    deg     = (int*)alloc(NN * 4);
  int*    rowptr  = (int*)alloc((NN + 1) * 4);
  int*    colx    = (int*)alloc(65536 * 4);
  int*    tricnt  = (int*)alloc(NN * 4);
  int*    triptr  = (int*)alloc((NN + 1) * 4);
  int2*   tri     = (int2*)alloc((size_t)TRI_CAP * 8);
  int*    segst   = (int*)alloc((NG + 1) * 4);
  int*    order   = (int*)alloc(NN * 4);
  float*  ent     = (float*)alloc(NN * 4);
  float*  V       = (float*)alloc(NN * 4);
  float*  p       = (float*)alloc(NN * 4);
  float*  q0      = (float*)alloc(NN * 4);
  float*  e0      = (float*)alloc(NN * 4);
  float*  agg1    = (float*)alloc(NN * 4);
  float*  scale   = (float*)alloc(HIDN * 4);
  float*  shift   = (float*)alloc(HIDN * 4);
  float*  tA      = (float*)alloc((size_t)NN * HIDN * 4);
  float*  tB      = (float*)alloc((size_t)NN * HIDN * 4);
  float*  tC      = (float*)alloc((size_t)NN * HIDN * 4);
  u8*     selb    = (u8*)alloc(NN);

  float* out    = (float*)d_out;
  float* o_x    = out;                       // 524288
  float* o_adj  = out + 524288;              // 4194304
  float* o_sel  = out + 4718592;             // 2048
  float* o_bat  = out + 4720640;             // 2048
  float* o_loss = out + 4722688;             // 1

  k_init<<<64, 256, 0, stream>>>(rowbits, segst);
  k_edges<<<128, 256, 0, stream>>>(ei, rowbits);
  k_deg<<<8, 256, 0, stream>>>(rowbits, deg, batch, segst);
  k_scan2048<<<1, 256, 0, stream>>>(deg, rowptr);
  k_extract<<<8, 256, 0, stream>>>(rowbits, rowptr, colx, tricnt);
  k_scan2048<<<1, 256, 0, stream>>>(tricnt, triptr);
  k_trifill<<<8, 256, 0, stream>>>(rowbits, rowptr, colx, triptr, tri);
  k_V<<<NN, 256, 0, stream>>>(x, rowptr, colx, V);
  k_soft<<<NG, 256, 0, stream>>>(V, segst, ent, seggam);

  // layer 1
  k_agg1<<<8, 256, 0, stream>>>(ent, rowptr, colx, agg1);
  k_lin1<<<1024, 256, 0, stream>>>(agg1, w11, b11, tA);
  k_bn<<<HIDN, 256, 0, stream>>>(tA, g1, be1, scale, shift);
  k_mm<1, 0><<<NN / 8, HIDN, 0, stream>>>(tA, w12, b12, scale, shift, tB);
  // layer 2
  k_agg128<<<NN, HIDN, 0, stream>>>(tB, rowptr, colx, tC);
  k_mm<0, 1><<<NN / 8, HIDN, 0, stream>>>(tC, w21, b21, scale, shift, tA);
  k_bn<<<HIDN, 256, 0, stream>>>(tA, g2, be2, scale, shift);
  k_mm<1, 0><<<NN / 8, HIDN, 0, stream>>>(tA, w22, b22, scale, shift, tB);
  // layer 3
  k_agg128<<<NN, HIDN, 0, stream>>>(tB, rowptr, colx, tC);
  k_mm<0, 1><<<NN / 8, HIDN, 0, stream>>>(tC, w31, b31, scale, shift, tA);
  k_bn<<<HIDN, 256, 0, stream>>>(tA, g3, be3, scale, shift);
  k_lin3<<<NN, HIDN, 0, stream>>>(tA, scale, shift, w32, b32, p);

  k_q0<<<8, 256, 0, stream>>>(p, ent, rowptr, colx, q0, e0);
  k_loss<<<1, 256, 0, stream>>>(ent, p, q0, seggam, scal);
  k_sort<<<1, 1024, 0, stream>>>(p, order);
  k_greedy<<<1, 1024, 0, stream>>>(rowptr, colx, triptr, tri, order, p, ent, q0, e0, scal, selb);

  k_reach<<<NN / 2, 64, 0, stream>>>(rowbits, rowptr, colx, row2);
  k_reach<<<NN / 2, 64, 0, stream>>>(row2, rowptr, colx, row3);
  k_out<<<NN * NN / 256, 256, 0, stream>>>(row2, row3, selb, x, batch, scal,
                                           o_x, o_adj, o_sel, o_bat, o_loss);

  (void)in_sizes; (void)n_in; (void)out_size; (void)ws_size;
}